// Round 2
// baseline (1019.592 us; speedup 1.0000x reference)
//
#include <hip/hip_runtime.h>
#include <math.h>

#define NPIX 1024   // H*W = 32*32

// ---------------------------------------------------------------------------
// Generic per-batch conv1x1 GEMM: out[b,o,n] = act(sum_c W[o,c]*in[b,c,n])
// 64x64 output tile, K-chunks of 16, 256 threads, 4x4 per thread. f32.
// Optional: per-channel scale/bias (affine), residual add.
// ---------------------------------------------------------------------------
__global__ __launch_bounds__(256) void conv1x1_kernel(
    const float* __restrict__ in, const float* __restrict__ W,
    const float* __restrict__ sc, const float* __restrict__ bi,
    const float* __restrict__ res, float* __restrict__ out,
    int O, int C) {
  const int b  = blockIdx.z;
  const int o0 = blockIdx.y << 6;
  const int n0 = blockIdx.x << 6;
  const float* inb  = in  + (size_t)b * C * NPIX;
  float*       outb = out + (size_t)b * O * NPIX;
  const float* resb = res ? res + (size_t)b * O * NPIX : nullptr;

  __shared__ float a_s[16][68];  // [k][o]  (row pad 68 -> 16B aligned float4)
  __shared__ float b_s[16][64];  // [k][n]
  const int t  = threadIdx.x;
  const int tn = t & 15, to = t >> 4;
  float acc[4][4] = {};

  for (int k0 = 0; k0 < C; k0 += 16) {
    {
      const int o = t & 63, kq = t >> 6;
      float4 w4 = *(const float4*)&W[(size_t)(o0 + o) * C + k0 + (kq << 2)];
      a_s[(kq << 2) + 0][o] = w4.x;
      a_s[(kq << 2) + 1][o] = w4.y;
      a_s[(kq << 2) + 2][o] = w4.z;
      a_s[(kq << 2) + 3][o] = w4.w;
      const int kk = t >> 4, nn = t & 15;
      *(float4*)&b_s[kk][nn << 2] =
          *(const float4*)&inb[(size_t)(k0 + kk) * NPIX + n0 + (nn << 2)];
    }
    __syncthreads();
#pragma unroll
    for (int kk = 0; kk < 16; ++kk) {
      float4 a4 = *(float4*)&a_s[kk][to << 2];
      float4 b4 = *(float4*)&b_s[kk][tn << 2];
      float av[4] = {a4.x, a4.y, a4.z, a4.w};
      float bv[4] = {b4.x, b4.y, b4.z, b4.w};
#pragma unroll
      for (int i = 0; i < 4; ++i)
#pragma unroll
        for (int j = 0; j < 4; ++j)
          acc[i][j] = fmaf(av[i], bv[j], acc[i][j]);
    }
    __syncthreads();
  }
#pragma unroll
  for (int i = 0; i < 4; ++i) {
    const int o  = o0 + (to << 2) + i;
    const float s  = sc ? sc[o] : 1.f;
    const float bb = bi ? bi[o] : 0.f;
    float v0 = fmaf(acc[i][0], s, bb);
    float v1 = fmaf(acc[i][1], s, bb);
    float v2 = fmaf(acc[i][2], s, bb);
    float v3 = fmaf(acc[i][3], s, bb);
    if (resb) {
      float4 rr = *(const float4*)&resb[(size_t)o * NPIX + n0 + (tn << 2)];
      v0 += rr.x; v1 += rr.y; v2 += rr.z; v3 += rr.w;
    }
    *(float4*)&outb[(size_t)o * NPIX + n0 + (tn << 2)] = make_float4(v0, v1, v2, v3);
  }
}

// ---------------------------------------------------------------------------
// Flash attention. qkv layout (B, 512, 1024): per head h rows h*128+{0..31 q,
// 32..63 k, 64..127 v}. Block = (b, h, 64-query tile). Online softmax over 16
// key tiles of 64. Thread (tq,tk): S rows tq*4+i, S cols tk*4+j; in PV phase
// d = tk + 16*j (spread rows -> 2-way LDS aliasing only).
// ---------------------------------------------------------------------------
__global__ __launch_bounds__(256) void attn_kernel(
    const float* __restrict__ qkv, float* __restrict__ outbuf) {
  const int n0 = blockIdx.x << 6;
  const int h  = blockIdx.y;
  const int b  = blockIdx.z;
  const float scale = 0.1767766952966369f;  // 1/sqrt(32)
  const float* base = qkv + ((size_t)b * 512 + h * 128) * NPIX;

  __shared__ float q_s[32][68];
  __shared__ float k_s[32][68];
  __shared__ float v_s[64][68];
  __shared__ float p_s[64][68];
  __shared__ float m_s[64], l_s[64], scl_s[64];

  const int t  = threadIdx.x;
  const int tq = t >> 4;   // 0..15  (query group)
  const int tk = t & 15;   // 0..15  (key group / d group)
  if (t < 64) { m_s[t] = -INFINITY; l_s[t] = 0.f; }

#pragma unroll
  for (int r = 0; r < 2; ++r) {
    int idx = t + (r << 8);  // 0..511
    int c = idx >> 4, nn = idx & 15;
    *(float4*)&q_s[c][nn << 2] =
        *(const float4*)&base[(size_t)c * NPIX + n0 + (nn << 2)];
  }
  float acc[4][4] = {};

  for (int mt = 0; mt < 16; ++mt) {
    const int m0 = mt << 6;
    __syncthreads();  // protect k/v/p reuse from previous iteration (covers init too)
#pragma unroll
    for (int r = 0; r < 2; ++r) {
      int idx = t + (r << 8);
      int c = idx >> 4, nn = idx & 15;
      *(float4*)&k_s[c][nn << 2] =
          *(const float4*)&base[(size_t)(32 + c) * NPIX + m0 + (nn << 2)];
    }
#pragma unroll
    for (int r = 0; r < 4; ++r) {
      int idx = t + (r << 8);  // 0..1023
      int c = idx >> 4, nn = idx & 15;
      *(float4*)&v_s[c][nn << 2] =
          *(const float4*)&base[(size_t)(64 + c) * NPIX + m0 + (nn << 2)];
    }
    __syncthreads();

    float s[4][4] = {};
#pragma unroll
    for (int c = 0; c < 32; ++c) {
      float4 q4 = *(float4*)&q_s[c][tq << 2];
      float4 k4 = *(float4*)&k_s[c][tk << 2];
      float qv[4] = {q4.x, q4.y, q4.z, q4.w};
      float kv[4] = {k4.x, k4.y, k4.z, k4.w};
#pragma unroll
      for (int i = 0; i < 4; ++i)
#pragma unroll
        for (int j = 0; j < 4; ++j)
          s[i][j] = fmaf(qv[i], kv[j], s[i][j]);
    }
#pragma unroll
    for (int i = 0; i < 4; ++i) {
      float rm = -INFINITY;
#pragma unroll
      for (int j = 0; j < 4; ++j) { s[i][j] *= scale; rm = fmaxf(rm, s[i][j]); }
#pragma unroll
      for (int off = 8; off >= 1; off >>= 1)
        rm = fmaxf(rm, __shfl_xor(rm, off, 16));
      const int ni = (tq << 2) + i;
      const float mold = m_s[ni];            // all 16 lanes read before lane0 writes
      const float mnew = fmaxf(mold, rm);
      float rs = 0.f;
#pragma unroll
      for (int j = 0; j < 4; ++j) { s[i][j] = __expf(s[i][j] - mnew); rs += s[i][j]; }
#pragma unroll
      for (int off = 8; off >= 1; off >>= 1)
        rs += __shfl_xor(rs, off, 16);
      if (tk == 0) {
        const float scl = __expf(mold - mnew);
        scl_s[ni] = scl;
        m_s[ni]   = mnew;
        l_s[ni]   = l_s[ni] * scl + rs;
      }
      *(float4*)&p_s[ni][tk << 2] = make_float4(s[i][0], s[i][1], s[i][2], s[i][3]);
    }
    __syncthreads();

#pragma unroll
    for (int i = 0; i < 4; ++i) {
      const float scl = scl_s[(tq << 2) + i];
#pragma unroll
      for (int j = 0; j < 4; ++j) acc[i][j] *= scl;
    }
#pragma unroll
    for (int m4 = 0; m4 < 16; ++m4) {
      float4 pp[4], vv[4];
#pragma unroll
      for (int i = 0; i < 4; ++i) pp[i] = *(float4*)&p_s[(tq << 2) + i][m4 << 2];
#pragma unroll
      for (int j = 0; j < 4; ++j) vv[j] = *(float4*)&v_s[tk + (j << 4)][m4 << 2];
#pragma unroll
      for (int i = 0; i < 4; ++i)
#pragma unroll
        for (int j = 0; j < 4; ++j)
          acc[i][j] += pp[i].x * vv[j].x + pp[i].y * vv[j].y +
                       pp[i].z * vv[j].z + pp[i].w * vv[j].w;
    }
  }
  __syncthreads();
  // normalize, stage transposed result in p_s[d][n_local]
#pragma unroll
  for (int i = 0; i < 4; ++i) {
    const float inv = 1.f / l_s[(tq << 2) + i];
#pragma unroll
    for (int j = 0; j < 4; ++j)
      p_s[tk + (j << 4)][(tq << 2) + i] = acc[i][j] * inv;
  }
  __syncthreads();
  const int d = t >> 2, nq = t & 3;
  float* op = outbuf + ((size_t)b * 256 + h * 64 + d) * NPIX + n0 + (nq << 4);
#pragma unroll
  for (int q4 = 0; q4 < 4; ++q4)
    *(float4*)&op[q4 << 2] = *(float4*)&p_s[d][(nq << 4) + (q4 << 2)];
}

// ---------------------------------------------------------------------------
// Depthwise 3x3 on v_img (= v slice of qkv) + affine; accumulate into att_buf.
// ---------------------------------------------------------------------------
__global__ __launch_bounds__(256) void pe_kernel(
    const float* __restrict__ qkv, const float* __restrict__ w,
    const float* __restrict__ s, const float* __restrict__ bi,
    float* __restrict__ att) {
  const int idx = blockIdx.x * 256 + threadIdx.x;  // B*256*1024
  const int pix = idx & 1023;
  const int ch  = (idx >> 10) & 255;
  const int b   = idx >> 18;
  const int hh = pix >> 5, ww = pix & 31;
  const int row = ((ch >> 6) * 128) + 64 + (ch & 63);  // v row in qkv
  const float* vimg = qkv + ((size_t)b * 512 + row) * NPIX;
  float acc = 0.f;
#pragma unroll
  for (int dy = -1; dy <= 1; ++dy)
#pragma unroll
    for (int dx = -1; dx <= 1; ++dx) {
      int y = hh + dy, x = ww + dx;
      if (y >= 0 && y < 32 && x >= 0 && x < 32)
        acc = fmaf(w[ch * 9 + (dy + 1) * 3 + (dx + 1)], vimg[(y << 5) + x], acc);
    }
  att[idx] += fmaf(acc, s[ch], bi[ch]);
}

// ---------------------------------------------------------------------------
// Depthwise 3x3 on y_pin (1024 ch) fused with GLU: g = gelu(dw(c)) * dw(c+512)
// ---------------------------------------------------------------------------
__global__ __launch_bounds__(256) void dwglu_kernel(
    const float* __restrict__ y, const float* __restrict__ w,
    float* __restrict__ g) {
  const int idx = blockIdx.x * 256 + threadIdx.x;  // B*512*1024
  const int pix = idx & 1023;
  const int c   = (idx >> 10) & 511;
  const int b   = idx >> 19;
  const int hh = pix >> 5, ww = pix & 31;
  const float* y1 = y + ((size_t)b * 1024 + c) * NPIX;
  const float* y2 = y1 + (size_t)512 * NPIX;
  const float* w1 = w + c * 9;
  const float* w2 = w + (512 + c) * 9;
  float s1 = 0.f, s2 = 0.f;
#pragma unroll
  for (int dy = -1; dy <= 1; ++dy)
#pragma unroll
    for (int dx = -1; dx <= 1; ++dx) {
      int yy = hh + dy, xx = ww + dx;
      if (yy >= 0 && yy < 32 && xx >= 0 && xx < 32) {
        const int off = (yy << 5) + xx;
        const int k = (dy + 1) * 3 + (dx + 1);
        s1 = fmaf(w1[k], y1[off], s1);
        s2 = fmaf(w2[k], y2[off], s2);
      }
    }
  const float ge = 0.5f * s1 * (1.f + erff(s1 * 0.70710678118654752f));
  g[idx] = ge * s2;
}

// ---------------------------------------------------------------------------
// Build per-channel 8x8 circular-conv kernel from the rfft2 filter:
// K[da,db] = (1/64) * sum_u sum_{v=0..4} c_v F[u,v] cos(2pi(u*da+v*db)/8)
// (exactly irfft2(rfft2(x)*F) for real F; identity delta when F==1).
// ---------------------------------------------------------------------------
__global__ __launch_bounds__(256) void kc_build(
    const float* __restrict__ filt, float* __restrict__ kc) {
  const int gid = blockIdx.x * 256 + threadIdx.x;  // 256*64
  const int c  = gid >> 6;
  const int da = (gid >> 3) & 7;
  const int db = gid & 7;
  const float* F = filt + c * 40;  // (8,5) per channel
  float acc = 0.f;
  for (int u = 0; u < 8; ++u)
    for (int v = 0; v <= 4; ++v) {
      const float wv = (v == 0 || v == 4) ? 1.f : 2.f;
      const int ph = (u * da + v * db) & 7;
      acc += wv * F[u * 5 + v] * cosf(0.78539816339744831f * (float)ph);
    }
  kc[gid] = acc * (1.f / 64.f);
}

// ---------------------------------------------------------------------------
// Apply per-channel 8x8 circular conv per spatial tile + final residual add.
// Block handles 4 tiles of one (b,c). 16 tiles per image.
// ---------------------------------------------------------------------------
__global__ __launch_bounds__(256) void fft_final_kernel(
    const float* __restrict__ yin, const float* __restrict__ x2,
    const float* __restrict__ kc, float* __restrict__ out) {
  const int bid = blockIdx.x;  // b*1024 + c*4 + gq
  const int gq = bid & 3;
  const int c  = (bid >> 2) & 255;
  const int b  = bid >> 10;
  __shared__ float kc_s[64];
  __shared__ float tile_s[4][64];
  const int t = threadIdx.x;
  if (t < 64) kc_s[t] = kc[(c << 6) + t];
  const int tl   = t >> 6;
  const int tile = (gq << 2) + tl;
  const int hb = tile >> 2, wb = tile & 3;
  const int a = (t >> 3) & 7, bb2 = t & 7;
  const size_t pbase = ((size_t)b * 256 + c) * NPIX;
  const size_t off = pbase + (size_t)((hb << 3) + a) * 32 + (wb << 3) + bb2;
  tile_s[tl][(a << 3) + bb2] = yin[off];
  __syncthreads();
  float acc = 0.f;
#pragma unroll
  for (int ap = 0; ap < 8; ++ap)
#pragma unroll
    for (int bp = 0; bp < 8; ++bp)
      acc = fmaf(kc_s[(((a - ap) & 7) << 3) + ((bb2 - bp) & 7)],
                 tile_s[tl][(ap << 3) + bp], acc);
  out[off] = x2[off] + acc;
}

// ---------------------------------------------------------------------------
extern "C" void kernel_launch(void* const* d_in, const int* in_sizes, int n_in,
                              void* d_out, int out_size, void* d_ws, size_t ws_size,
                              hipStream_t stream) {
  const float* x      = (const float*)d_in[0];
  const float* qkv_w  = (const float*)d_in[1];
  const float* qkv_s  = (const float*)d_in[2];
  const float* qkv_b  = (const float*)d_in[3];
  const float* pe_w   = (const float*)d_in[4];
  const float* pe_s   = (const float*)d_in[5];
  const float* pe_b   = (const float*)d_in[6];
  const float* proj_w = (const float*)d_in[7];
  const float* proj_s = (const float*)d_in[8];
  const float* proj_b = (const float*)d_in[9];
  const float* pin_w  = (const float*)d_in[10];
  const float* dw_w   = (const float*)d_in[11];
  const float* filt   = (const float*)d_in[12];
  const float* pout_w = (const float*)d_in[13];
  float* out = (float*)d_out;
  float* ws  = (float*)d_ws;

  // workspace layout (floats); peak ~128 MB with reuse
  float* qkv_buf = ws;                   // 16*512*1024 = 8388608
  float* att_buf = ws + 8388608;         // 16*256*1024 = 4194304
  float* x2      = ws + 12582912;        // 4194304
  float* y_pin   = ws + 16777216;        // 16*1024*1024 = 16777216
  float* g_buf   = ws;                   // reuse qkv region (qkv dead after pe)
  float* y_out   = ws + 8388608;         // reuse att region (att dead after proj)
  float* kc      = ws + 33554432;        // 256*64

  dim3 blk(256);
  kc_build<<<dim3(64), blk, 0, stream>>>(filt, kc);
  // qkv = affine(qkv_w @ x)
  conv1x1_kernel<<<dim3(16, 8, 16), blk, 0, stream>>>(
      x, qkv_w, qkv_s, qkv_b, nullptr, qkv_buf, 512, 256);
  // attention -> att_buf
  attn_kernel<<<dim3(16, 4, 16), blk, 0, stream>>>(qkv_buf, att_buf);
  // att_buf += affine(dwconv3x3(v_img))
  pe_kernel<<<dim3(16384), blk, 0, stream>>>(qkv_buf, pe_w, pe_s, pe_b, att_buf);
  // x2 = x + affine(proj_w @ att_buf)
  conv1x1_kernel<<<dim3(16, 4, 16), blk, 0, stream>>>(
      att_buf, proj_w, proj_s, proj_b, x, x2, 256, 256);
  // y_pin = pin_w @ x2
  conv1x1_kernel<<<dim3(16, 16, 16), blk, 0, stream>>>(
      x2, pin_w, nullptr, nullptr, nullptr, y_pin, 1024, 256);
  // g = gelu(dw(y1)) * dw(y2)
  dwglu_kernel<<<dim3(32768), blk, 0, stream>>>(y_pin, dw_w, g_buf);
  // y_out = pout_w @ g
  conv1x1_kernel<<<dim3(16, 4, 16), blk, 0, stream>>>(
      g_buf, pout_w, nullptr, nullptr, nullptr, y_out, 256, 512);
  // out = x2 + circconv8x8(y_out)
  fft_final_kernel<<<dim3(16384), blk, 0, stream>>>(y_out, x2, kc, out);
}

// Round 4
// 537.772 us; speedup vs baseline: 1.8960x; 1.8960x over previous
//
#include <hip/hip_runtime.h>
#include <math.h>

#define NPIX 1024   // H*W = 32*32

typedef __bf16 bf16x8 __attribute__((ext_vector_type(8)));
typedef float  f32x4  __attribute__((ext_vector_type(4)));

// ---------------------------------------------------------------------------
// Generic per-batch conv1x1 GEMM: out[b,o,n] = act(sum_c W[o,c]*in[b,c,n])
// 64x64 output tile, K-chunks of 16, 256 threads, 4x4 per thread. f32.
// ---------------------------------------------------------------------------
__global__ __launch_bounds__(256) void conv1x1_kernel(
    const float* __restrict__ in, const float* __restrict__ W,
    const float* __restrict__ sc, const float* __restrict__ bi,
    const float* __restrict__ res, float* __restrict__ out,
    int O, int C) {
  const int b  = blockIdx.z;
  const int o0 = blockIdx.y << 6;
  const int n0 = blockIdx.x << 6;
  const float* inb  = in  + (size_t)b * C * NPIX;
  float*       outb = out + (size_t)b * O * NPIX;
  const float* resb = res ? res + (size_t)b * O * NPIX : nullptr;

  __shared__ float a_s[16][68];
  __shared__ float b_s[16][64];
  const int t  = threadIdx.x;
  const int tn = t & 15, to = t >> 4;
  float acc[4][4] = {};

  for (int k0 = 0; k0 < C; k0 += 16) {
    {
      const int o = t & 63, kq = t >> 6;
      float4 w4 = *(const float4*)&W[(size_t)(o0 + o) * C + k0 + (kq << 2)];
      a_s[(kq << 2) + 0][o] = w4.x;
      a_s[(kq << 2) + 1][o] = w4.y;
      a_s[(kq << 2) + 2][o] = w4.z;
      a_s[(kq << 2) + 3][o] = w4.w;
      const int kk = t >> 4, nn = t & 15;
      *(float4*)&b_s[kk][nn << 2] =
          *(const float4*)&inb[(size_t)(k0 + kk) * NPIX + n0 + (nn << 2)];
    }
    __syncthreads();
#pragma unroll
    for (int kk = 0; kk < 16; ++kk) {
      float4 a4 = *(float4*)&a_s[kk][to << 2];
      float4 b4 = *(float4*)&b_s[kk][tn << 2];
      float av[4] = {a4.x, a4.y, a4.z, a4.w};
      float bv[4] = {b4.x, b4.y, b4.z, b4.w};
#pragma unroll
      for (int i = 0; i < 4; ++i)
#pragma unroll
        for (int j = 0; j < 4; ++j)
          acc[i][j] = fmaf(av[i], bv[j], acc[i][j]);
    }
    __syncthreads();
  }
#pragma unroll
  for (int i = 0; i < 4; ++i) {
    const int o  = o0 + (to << 2) + i;
    const float s  = sc ? sc[o] : 1.f;
    const float bb = bi ? bi[o] : 0.f;
    float v0 = fmaf(acc[i][0], s, bb);
    float v1 = fmaf(acc[i][1], s, bb);
    float v2 = fmaf(acc[i][2], s, bb);
    float v3 = fmaf(acc[i][3], s, bb);
    if (resb) {
      float4 rr = *(const float4*)&resb[(size_t)o * NPIX + n0 + (tn << 2)];
      v0 += rr.x; v1 += rr.y; v2 += rr.z; v3 += rr.w;
    }
    *(float4*)&outb[(size_t)o * NPIX + n0 + (tn << 2)] = make_float4(v0, v1, v2, v3);
  }
}

// ---------------------------------------------------------------------------
// bf16-MFMA flash attention. qkv layout (B,512,1024): head h rows h*128 +
// {0..31 q, 32..63 k, 64..127 v}. Block = (b, h, 64-query tile), 4 waves,
// wave w owns queries n0+16w..+15.
//
// QK^T swapped: S^T-tile = mfma(A=KT[16m x 32c], B=Q[32c x 16q]) so the
// query index = D-frag col = lane&15 -> per-query softmax is in-lane (16
// vals) + shfl_xor(16,32). PV: out^T = mfma(A=V[16d x 32m], B=P^T-frag),
// P^T-frag built by 16 shuffles + select per K-step (both candidate tiles
// shuffled, target selects by its own bit5).
// ---------------------------------------------------------------------------
__global__ __launch_bounds__(256) void attn_mfma_kernel(
    const float* __restrict__ qkv, float* __restrict__ outbuf) {
  const int n0 = blockIdx.x << 6;
  const int h  = blockIdx.y;
  const int b  = blockIdx.z;
  const float scale = 0.1767766952966369f;  // 1/sqrt(32)
  const float* base = qkv + ((size_t)b * 512 + h * 128) * NPIX;

  __shared__ __align__(16) __bf16 kt_s[64][40];         // KT[m][c], 80-B rows
  __shared__ __align__(16) unsigned int v_su[64 * 32];  // V[d][m] bf16, XOR-swz

  const int t    = threadIdx.x;
  const int w    = t >> 6;
  const int lane = t & 63;
  const int lq   = lane & 15;
  const int g    = lane >> 4;

  // Q B-frag (persistent): q[c=8g+j][n0+16w+lq] * scale
  bf16x8 qf;
  {
    const float* qp = base + (size_t)(g << 3) * NPIX + n0 + (w << 4) + lq;
#pragma unroll
    for (int j = 0; j < 8; ++j)
      qf[j] = (__bf16)(qp[(size_t)j * NPIX] * scale);
  }

  // staging thread roles
  const int kc_ = t >> 3;            // 0..31 (channel)
  const int kmb = (t & 7) << 3;      // m base (8 per thread)
  const float* krow = base + (size_t)(32 + kc_) * NPIX;
  const int vd  = t >> 2;            // 0..63 (d row)
  const int vmb = (t & 3) << 4;      // m base (16 per thread)
  const float* vrow = base + (size_t)(64 + vd) * NPIX;
  const int vswz = (vd & 7) << 4;    // byte XOR for V rows

  float m_run = -3.0e38f, l_run = 0.f;
  f32x4 acc0 = {0.f, 0.f, 0.f, 0.f}, acc1 = acc0, acc2 = acc0, acc3 = acc0;

  const int laneA = ((lane & 16) << 1) | lq;   // 32*(g&1) + lq
  const bool hi5  = (lane & 32) != 0;

  for (int mt = 0; mt < 16; ++mt) {
    const int m0 = mt << 6;
    __syncthreads();  // previous tile's reads done before overwrite
    // ---- stage KT (bf16, transposed) ----
#pragma unroll
    for (int i2 = 0; i2 < 2; ++i2) {
      float4 k4 = *(const float4*)&krow[m0 + kmb + (i2 << 2)];
      kt_s[kmb + (i2 << 2) + 0][kc_] = (__bf16)k4.x;
      kt_s[kmb + (i2 << 2) + 1][kc_] = (__bf16)k4.y;
      kt_s[kmb + (i2 << 2) + 2][kc_] = (__bf16)k4.z;
      kt_s[kmb + (i2 << 2) + 3][kc_] = (__bf16)k4.w;
    }
    // ---- stage V (bf16, swizzled) ----
#pragma unroll
    for (int i4 = 0; i4 < 4; ++i4) {
      float4 v4 = *(const float4*)&vrow[m0 + vmb + (i4 << 2)];
      union { __bf16 h[4]; uint2 u; } pk;
      pk.h[0] = (__bf16)v4.x; pk.h[1] = (__bf16)v4.y;
      pk.h[2] = (__bf16)v4.z; pk.h[3] = (__bf16)v4.w;
      const int mby = (vmb + (i4 << 2)) << 1;  // byte col = 2*m (mult of 8)
      *(uint2*)((char*)v_su + (vd << 7) + (mby ^ vswz)) = pk.u;
    }
    __syncthreads();

    // ---- QK^T (swapped): st[tt] = S^T[16tt+4g+r][q=lq], scaled ----
    f32x4 st[4];
#pragma unroll
    for (int tt = 0; tt < 4; ++tt) {
      bf16x8 kfrag = *(const bf16x8*)&kt_s[(tt << 4) + lq][g << 3];
      st[tt] = __builtin_amdgcn_mfma_f32_16x16x32_bf16(
          kfrag, qf, (f32x4){0.f, 0.f, 0.f, 0.f}, 0, 0, 0);
    }

    // ---- online softmax (per query = per lane col) ----
    float tmax = -3.0e38f;
#pragma unroll
    for (int tt = 0; tt < 4; ++tt)
#pragma unroll
      for (int r = 0; r < 4; ++r) tmax = fmaxf(tmax, st[tt][r]);
    tmax = fmaxf(tmax, __shfl_xor(tmax, 16));
    tmax = fmaxf(tmax, __shfl_xor(tmax, 32));
    const float mnew  = fmaxf(m_run, tmax);
    const float alpha = __expf(m_run - mnew);
    float ssum = 0.f;
#pragma unroll
    for (int tt = 0; tt < 4; ++tt)
#pragma unroll
      for (int r = 0; r < 4; ++r) {
        st[tt][r] = __expf(st[tt][r] - mnew);
        ssum += st[tt][r];
      }
    ssum += __shfl_xor(ssum, 16);
    ssum += __shfl_xor(ssum, 32);
    l_run = l_run * alpha + ssum;
    m_run = mnew;
    acc0 *= alpha; acc1 *= alpha; acc2 *= alpha; acc3 *= alpha;

    // ---- PV: out^T += mfma(V-frag, P^T-frag) ----
#pragma unroll
    for (int s = 0; s < 2; ++s) {
      bf16x8 pf;
#pragma unroll
      for (int r = 0; r < 4; ++r) {
        const float aL = __shfl(st[2 * s][r],     laneA);
        const float aH = __shfl(st[2 * s + 1][r], laneA);
        const float bL = __shfl(st[2 * s][r],     laneA + 16);
        const float bH = __shfl(st[2 * s + 1][r], laneA + 16);
        pf[r]     = (__bf16)(hi5 ? aH : aL);
        pf[r + 4] = (__bf16)(hi5 ? bH : bL);
      }
      const int cb = ((g << 4) + (s << 6));
#pragma unroll
      for (int dt = 0; dt < 4; ++dt) {
        const int row = (dt << 4) + lq;
        const bf16x8 vfrag = *(const bf16x8*)(
            (const char*)v_su + (row << 7) + (cb ^ ((lq & 7) << 4)));
        f32x4& a = (dt == 0) ? acc0 : (dt == 1) ? acc1 : (dt == 2) ? acc2 : acc3;
        a = __builtin_amdgcn_mfma_f32_16x16x32_bf16(vfrag, pf, a, 0, 0, 0);
      }
    }
  }

  // ---- epilogue: out[d][n] = acc^T / l ----
  const float inv = 1.f / l_run;
  float* op = outbuf + ((size_t)b * 256 + h * 64) * NPIX + n0 + (w << 4) + lq;
#pragma unroll
  for (int r = 0; r < 4; ++r) {
    op[(size_t)((0 << 4) + (g << 2) + r) * NPIX] = acc0[r] * inv;
    op[(size_t)((1 << 4) + (g << 2) + r) * NPIX] = acc1[r] * inv;
    op[(size_t)((2 << 4) + (g << 2) + r) * NPIX] = acc2[r] * inv;
    op[(size_t)((3 << 4) + (g << 2) + r) * NPIX] = acc3[r] * inv;
  }
}

// ---------------------------------------------------------------------------
// Depthwise 3x3 on v_img (= v slice of qkv) + affine; accumulate into att_buf.
// ---------------------------------------------------------------------------
__global__ __launch_bounds__(256) void pe_kernel(
    const float* __restrict__ qkv, const float* __restrict__ w,
    const float* __restrict__ s, const float* __restrict__ bi,
    float* __restrict__ att) {
  const int idx = blockIdx.x * 256 + threadIdx.x;
  const int pix = idx & 1023;
  const int ch  = (idx >> 10) & 255;
  const int b   = idx >> 18;
  const int hh = pix >> 5, ww = pix & 31;
  const int row = ((ch >> 6) * 128) + 64 + (ch & 63);
  const float* vimg = qkv + ((size_t)b * 512 + row) * NPIX;
  float acc = 0.f;
#pragma unroll
  for (int dy = -1; dy <= 1; ++dy)
#pragma unroll
    for (int dx = -1; dx <= 1; ++dx) {
      int y = hh + dy, x = ww + dx;
      if (y >= 0 && y < 32 && x >= 0 && x < 32)
        acc = fmaf(w[ch * 9 + (dy + 1) * 3 + (dx + 1)], vimg[(y << 5) + x], acc);
    }
  att[idx] += fmaf(acc, s[ch], bi[ch]);
}

// ---------------------------------------------------------------------------
// Depthwise 3x3 on y_pin (1024 ch) fused with GLU: g = gelu(dw(c)) * dw(c+512)
// ---------------------------------------------------------------------------
__global__ __launch_bounds__(256) void dwglu_kernel(
    const float* __restrict__ y, const float* __restrict__ w,
    float* __restrict__ g) {
  const int idx = blockIdx.x * 256 + threadIdx.x;
  const int pix = idx & 1023;
  const int c   = (idx >> 10) & 511;
  const int b   = idx >> 19;
  const int hh = pix >> 5, ww = pix & 31;
  const float* y1 = y + ((size_t)b * 1024 + c) * NPIX;
  const float* y2 = y1 + (size_t)512 * NPIX;
  const float* w1 = w + c * 9;
  const float* w2 = w + (512 + c) * 9;
  float s1 = 0.f, s2 = 0.f;
#pragma unroll
  for (int dy = -1; dy <= 1; ++dy)
#pragma unroll
    for (int dx = -1; dx <= 1; ++dx) {
      int yy = hh + dy, xx = ww + dx;
      if (yy >= 0 && yy < 32 && xx >= 0 && xx < 32) {
        const int off = (yy << 5) + xx;
        const int k = (dy + 1) * 3 + (dx + 1);
        s1 = fmaf(w1[k], y1[off], s1);
        s2 = fmaf(w2[k], y2[off], s2);
      }
    }
  const float ge = 0.5f * s1 * (1.f + erff(s1 * 0.70710678118654752f));
  g[idx] = ge * s2;
}

// ---------------------------------------------------------------------------
// Build per-channel 8x8 circular-conv kernel from the rfft2 filter.
// ---------------------------------------------------------------------------
__global__ __launch_bounds__(256) void kc_build(
    const float* __restrict__ filt, float* __restrict__ kc) {
  const int gid = blockIdx.x * 256 + threadIdx.x;
  const int c  = gid >> 6;
  const int da = (gid >> 3) & 7;
  const int db = gid & 7;
  const float* F = filt + c * 40;
  float acc = 0.f;
  for (int u = 0; u < 8; ++u)
    for (int v = 0; v <= 4; ++v) {
      const float wv = (v == 0 || v == 4) ? 1.f : 2.f;
      const int ph = (u * da + v * db) & 7;
      acc += wv * F[u * 5 + v] * cosf(0.78539816339744831f * (float)ph);
    }
  kc[gid] = acc * (1.f / 64.f);
}

// ---------------------------------------------------------------------------
// Apply per-channel 8x8 circular conv per spatial tile + final residual add.
// ---------------------------------------------------------------------------
__global__ __launch_bounds__(256) void fft_final_kernel(
    const float* __restrict__ yin, const float* __restrict__ x2,
    const float* __restrict__ kc, float* __restrict__ out) {
  const int bid = blockIdx.x;
  const int gq = bid & 3;
  const int c  = (bid >> 2) & 255;
  const int b  = bid >> 10;
  __shared__ float kc_s[64];
  __shared__ float tile_s[4][64];
  const int t = threadIdx.x;
  if (t < 64) kc_s[t] = kc[(c << 6) + t];
  const int tl   = t >> 6;
  const int tile = (gq << 2) + tl;
  const int hb = tile >> 2, wb = tile & 3;
  const int a = (t >> 3) & 7, bb2 = t & 7;
  const size_t pbase = ((size_t)b * 256 + c) * NPIX;
  const size_t off = pbase + (size_t)((hb << 3) + a) * 32 + (wb << 3) + bb2;
  tile_s[tl][(a << 3) + bb2] = yin[off];
  __syncthreads();
  float acc = 0.f;
#pragma unroll
  for (int ap = 0; ap < 8; ++ap)
#pragma unroll
    for (int bp = 0; bp < 8; ++bp)
      acc = fmaf(kc_s[(((a - ap) & 7) << 3) + ((bb2 - bp) & 7)],
                 tile_s[tl][(ap << 3) + bp], acc);
  out[off] = x2[off] + acc;
}

// ---------------------------------------------------------------------------
extern "C" void kernel_launch(void* const* d_in, const int* in_sizes, int n_in,
                              void* d_out, int out_size, void* d_ws, size_t ws_size,
                              hipStream_t stream) {
  const float* x      = (const float*)d_in[0];
  const float* qkv_w  = (const float*)d_in[1];
  const float* qkv_s  = (const float*)d_in[2];
  const float* qkv_b  = (const float*)d_in[3];
  const float* pe_w   = (const float*)d_in[4];
  const float* pe_s   = (const float*)d_in[5];
  const float* pe_b   = (const float*)d_in[6];
  const float* proj_w = (const float*)d_in[7];
  const float* proj_s = (const float*)d_in[8];
  const float* proj_b = (const float*)d_in[9];
  const float* pin_w  = (const float*)d_in[10];
  const float* dw_w   = (const float*)d_in[11];
  const float* filt   = (const float*)d_in[12];
  const float* pout_w = (const float*)d_in[13];
  float* out = (float*)d_out;
  float* ws  = (float*)d_ws;

  float* qkv_buf = ws;                   // 16*512*1024
  float* att_buf = ws + 8388608;         // 16*256*1024
  float* x2      = ws + 12582912;        // 16*256*1024
  float* y_pin   = ws + 16777216;        // 16*1024*1024
  float* g_buf   = ws;                   // reuse qkv region
  float* y_out   = ws + 8388608;         // reuse att region
  float* kc      = ws + 33554432;        // 256*64

  dim3 blk(256);
  kc_build<<<dim3(64), blk, 0, stream>>>(filt, kc);
  conv1x1_kernel<<<dim3(16, 8, 16), blk, 0, stream>>>(
      x, qkv_w, qkv_s, qkv_b, nullptr, qkv_buf, 512, 256);
  attn_mfma_kernel<<<dim3(16, 4, 16), blk, 0, stream>>>(qkv_buf, att_buf);
  pe_kernel<<<dim3(16384), blk, 0, stream>>>(qkv_buf, pe_w, pe_s, pe_b, att_buf);
  conv1x1_kernel<<<dim3(16, 4, 16), blk, 0, stream>>>(
      att_buf, proj_w, proj_s, proj_b, x, x2, 256, 256);
  conv1x1_kernel<<<dim3(16, 16, 16), blk, 0, stream>>>(
      x2, pin_w, nullptr, nullptr, nullptr, y_pin, 1024, 256);
  dwglu_kernel<<<dim3(32768), blk, 0, stream>>>(y_pin, dw_w, g_buf);
  conv1x1_kernel<<<dim3(16, 4, 16), blk, 0, stream>>>(
      g_buf, pout_w, nullptr, nullptr, nullptr, y_out, 256, 512);
  fft_final_kernel<<<dim3(16384), blk, 0, stream>>>(y_out, x2, kc, out);
}

// Round 5
// 371.758 us; speedup vs baseline: 2.7426x; 1.4466x over previous
//
#include <hip/hip_runtime.h>
#include <math.h>

#define NPIX 1024   // H*W = 32*32

typedef __bf16 bf16x8 __attribute__((ext_vector_type(8)));
typedef float  f32x4  __attribute__((ext_vector_type(4)));

// ---------------------------------------------------------------------------
// bf16-MFMA conv1x1 GEMM: out[b,o,n] = sc[o]*(sum_c W[o,c]*in[b,c,n])+bi[o]
// (+res). 128x128 tile, K-step 32, 4 waves (2x2), wave tile 64x64 = 4x4
// frags of mfma_f32_16x16x32_bf16. LDS rows padded to 80 B -> 2-way banks.
// A = W[o][k] (no transpose), B = in transposed to [n][k] at staging.
// ---------------------------------------------------------------------------
__global__ __launch_bounds__(256) void conv1x1_mfma_kernel(
    const float* __restrict__ in, const float* __restrict__ W,
    const float* __restrict__ sc, const float* __restrict__ bi,
    const float* __restrict__ res, float* __restrict__ out,
    int O, int C) {
  const int b  = blockIdx.z;
  const int o0 = blockIdx.y << 7;
  const int n0 = blockIdx.x << 7;
  const float* inb  = in  + (size_t)b * C * NPIX;
  float*       outb = out + (size_t)b * O * NPIX;
  const float* resb = res ? res + (size_t)b * O * NPIX : nullptr;

  __shared__ __align__(16) __bf16 a_s[128][40];  // [o][k], 80-B pitch
  __shared__ __align__(16) __bf16 b_s[128][40];  // [n][k], 80-B pitch

  const int t    = threadIdx.x;
  const int lane = t & 63;
  const int wv   = t >> 6;
  const int wo   = (wv >> 1) << 6;   // wave o-offset: 0 / 64
  const int wn   = (wv & 1) << 6;    // wave n-offset: 0 / 64
  const int lr   = lane & 15;
  const int g    = lane >> 4;

  // staging roles
  const int ao = t >> 1, ak = (t & 1) << 4;   // A: row ao, k-half ak
  const int bn = t & 127, bk = (t >> 7) << 4; // B: row bn, k-half bk
  const float* wrow = &W[(size_t)(o0 + ao) * C];

  f32x4 acc[4][4];
#pragma unroll
  for (int m = 0; m < 4; ++m)
#pragma unroll
    for (int n = 0; n < 4; ++n) acc[m][n] = (f32x4){0.f, 0.f, 0.f, 0.f};

  for (int k0 = 0; k0 < C; k0 += 32) {
    __syncthreads();  // previous step's fragment reads done
    // ---- stage A: 16 f32 -> bf16, two 16-B LDS writes ----
    {
      const float* wp = wrow + k0 + ak;
#pragma unroll
      for (int half = 0; half < 2; ++half) {
        float4 lo = *(const float4*)&wp[half * 8];
        float4 hi = *(const float4*)&wp[half * 8 + 4];
        union { __bf16 h[8]; uint4 u; } pk;
        pk.h[0] = (__bf16)lo.x; pk.h[1] = (__bf16)lo.y;
        pk.h[2] = (__bf16)lo.z; pk.h[3] = (__bf16)lo.w;
        pk.h[4] = (__bf16)hi.x; pk.h[5] = (__bf16)hi.y;
        pk.h[6] = (__bf16)hi.z; pk.h[7] = (__bf16)hi.w;
        *(uint4*)((char*)&a_s[ao][ak] + half * 16) = pk.u;
      }
    }
    // ---- stage B: transpose [k][n] -> [n][k], 4x (4 loads -> 8-B write) ----
    {
#pragma unroll
      for (int p = 0; p < 4; ++p) {
        const int kk = k0 + bk + (p << 2);
        union { __bf16 h[4]; uint2 u; } pk;
        pk.h[0] = (__bf16)inb[(size_t)(kk + 0) * NPIX + n0 + bn];
        pk.h[1] = (__bf16)inb[(size_t)(kk + 1) * NPIX + n0 + bn];
        pk.h[2] = (__bf16)inb[(size_t)(kk + 2) * NPIX + n0 + bn];
        pk.h[3] = (__bf16)inb[(size_t)(kk + 3) * NPIX + n0 + bn];
        *(uint2*)((char*)&b_s[bn][bk] + (p << 3)) = pk.u;
      }
    }
    __syncthreads();
    // ---- fragments + 16 MFMAs ----
    bf16x8 af[4], bfr[4];
#pragma unroll
    for (int m = 0; m < 4; ++m)
      af[m] = *(const bf16x8*)((const char*)&a_s[wo + (m << 4) + lr][0] + (g << 4));
#pragma unroll
    for (int n = 0; n < 4; ++n)
      bfr[n] = *(const bf16x8*)((const char*)&b_s[wn + (n << 4) + lr][0] + (g << 4));
#pragma unroll
    for (int m = 0; m < 4; ++m)
#pragma unroll
      for (int n = 0; n < 4; ++n)
        acc[m][n] = __builtin_amdgcn_mfma_f32_16x16x32_bf16(
            af[m], bfr[n], acc[m][n], 0, 0, 0);
  }

  // ---- epilogue: scale/bias/residual in f32, coalesced stores ----
#pragma unroll
  for (int m = 0; m < 4; ++m) {
#pragma unroll
    for (int r = 0; r < 4; ++r) {
      const int o = o0 + wo + (m << 4) + (g << 2) + r;
      const float s  = sc ? sc[o] : 1.f;
      const float bb = bi ? bi[o] : 0.f;
      float* orow = &outb[(size_t)o * NPIX];
      const float* rrow = resb ? &resb[(size_t)o * NPIX] : nullptr;
#pragma unroll
      for (int n = 0; n < 4; ++n) {
        const int nn = n0 + wn + (n << 4) + lr;
        float v = fmaf(acc[m][n][r], s, bb);
        if (rrow) v += rrow[nn];
        orow[nn] = v;
      }
    }
  }
}

// ---------------------------------------------------------------------------
// bf16-MFMA flash attention (unchanged from Round 4; see derivation notes).
// ---------------------------------------------------------------------------
__global__ __launch_bounds__(256) void attn_mfma_kernel(
    const float* __restrict__ qkv, float* __restrict__ outbuf) {
  const int n0 = blockIdx.x << 6;
  const int h  = blockIdx.y;
  const int b  = blockIdx.z;
  const float scale = 0.1767766952966369f;  // 1/sqrt(32)
  const float* base = qkv + ((size_t)b * 512 + h * 128) * NPIX;

  __shared__ __align__(16) __bf16 kt_s[64][40];         // KT[m][c], 80-B rows
  __shared__ __align__(16) unsigned int v_su[64 * 32];  // V[d][m] bf16, XOR-swz

  const int t    = threadIdx.x;
  const int w    = t >> 6;
  const int lane = t & 63;
  const int lq   = lane & 15;
  const int g    = lane >> 4;

  bf16x8 qf;
  {
    const float* qp = base + (size_t)(g << 3) * NPIX + n0 + (w << 4) + lq;
#pragma unroll
    for (int j = 0; j < 8; ++j)
      qf[j] = (__bf16)(qp[(size_t)j * NPIX] * scale);
  }

  const int kc_ = t >> 3;
  const int kmb = (t & 7) << 3;
  const float* krow = base + (size_t)(32 + kc_) * NPIX;
  const int vd  = t >> 2;
  const int vmb = (t & 3) << 4;
  const float* vrow = base + (size_t)(64 + vd) * NPIX;
  const int vswz = (vd & 7) << 4;

  float m_run = -3.0e38f, l_run = 0.f;
  f32x4 acc0 = {0.f, 0.f, 0.f, 0.f}, acc1 = acc0, acc2 = acc0, acc3 = acc0;

  const int laneA = ((lane & 16) << 1) | lq;
  const bool hi5  = (lane & 32) != 0;

  for (int mt = 0; mt < 16; ++mt) {
    const int m0 = mt << 6;
    __syncthreads();
#pragma unroll
    for (int i2 = 0; i2 < 2; ++i2) {
      float4 k4 = *(const float4*)&krow[m0 + kmb + (i2 << 2)];
      kt_s[kmb + (i2 << 2) + 0][kc_] = (__bf16)k4.x;
      kt_s[kmb + (i2 << 2) + 1][kc_] = (__bf16)k4.y;
      kt_s[kmb + (i2 << 2) + 2][kc_] = (__bf16)k4.z;
      kt_s[kmb + (i2 << 2) + 3][kc_] = (__bf16)k4.w;
    }
#pragma unroll
    for (int i4 = 0; i4 < 4; ++i4) {
      float4 v4 = *(const float4*)&vrow[m0 + vmb + (i4 << 2)];
      union { __bf16 h[4]; uint2 u; } pk;
      pk.h[0] = (__bf16)v4.x; pk.h[1] = (__bf16)v4.y;
      pk.h[2] = (__bf16)v4.z; pk.h[3] = (__bf16)v4.w;
      const int mby = (vmb + (i4 << 2)) << 1;
      *(uint2*)((char*)v_su + (vd << 7) + (mby ^ vswz)) = pk.u;
    }
    __syncthreads();

    f32x4 st[4];
#pragma unroll
    for (int tt = 0; tt < 4; ++tt) {
      bf16x8 kfrag = *(const bf16x8*)&kt_s[(tt << 4) + lq][g << 3];
      st[tt] = __builtin_amdgcn_mfma_f32_16x16x32_bf16(
          kfrag, qf, (f32x4){0.f, 0.f, 0.f, 0.f}, 0, 0, 0);
    }

    float tmax = -3.0e38f;
#pragma unroll
    for (int tt = 0; tt < 4; ++tt)
#pragma unroll
      for (int r = 0; r < 4; ++r) tmax = fmaxf(tmax, st[tt][r]);
    tmax = fmaxf(tmax, __shfl_xor(tmax, 16));
    tmax = fmaxf(tmax, __shfl_xor(tmax, 32));
    const float mnew  = fmaxf(m_run, tmax);
    const float alpha = __expf(m_run - mnew);
    float ssum = 0.f;
#pragma unroll
    for (int tt = 0; tt < 4; ++tt)
#pragma unroll
      for (int r = 0; r < 4; ++r) {
        st[tt][r] = __expf(st[tt][r] - mnew);
        ssum += st[tt][r];
      }
    ssum += __shfl_xor(ssum, 16);
    ssum += __shfl_xor(ssum, 32);
    l_run = l_run * alpha + ssum;
    m_run = mnew;
    acc0 *= alpha; acc1 *= alpha; acc2 *= alpha; acc3 *= alpha;

#pragma unroll
    for (int s = 0; s < 2; ++s) {
      bf16x8 pf;
#pragma unroll
      for (int r = 0; r < 4; ++r) {
        const float aL = __shfl(st[2 * s][r],     laneA);
        const float aH = __shfl(st[2 * s + 1][r], laneA);
        const float bL = __shfl(st[2 * s][r],     laneA + 16);
        const float bH = __shfl(st[2 * s + 1][r], laneA + 16);
        pf[r]     = (__bf16)(hi5 ? aH : aL);
        pf[r + 4] = (__bf16)(hi5 ? bH : bL);
      }
      const int cb = ((g << 4) + (s << 6));
#pragma unroll
      for (int dt = 0; dt < 4; ++dt) {
        const int row = (dt << 4) + lq;
        const bf16x8 vfrag = *(const bf16x8*)(
            (const char*)v_su + (row << 7) + (cb ^ ((lq & 7) << 4)));
        f32x4& a = (dt == 0) ? acc0 : (dt == 1) ? acc1 : (dt == 2) ? acc2 : acc3;
        a = __builtin_amdgcn_mfma_f32_16x16x32_bf16(vfrag, pf, a, 0, 0, 0);
      }
    }
  }

  const float inv = 1.f / l_run;
  float* op = outbuf + ((size_t)b * 256 + h * 64) * NPIX + n0 + (w << 4) + lq;
#pragma unroll
  for (int r = 0; r < 4; ++r) {
    op[(size_t)((0 << 4) + (g << 2) + r) * NPIX] = acc0[r] * inv;
    op[(size_t)((1 << 4) + (g << 2) + r) * NPIX] = acc1[r] * inv;
    op[(size_t)((2 << 4) + (g << 2) + r) * NPIX] = acc2[r] * inv;
    op[(size_t)((3 << 4) + (g << 2) + r) * NPIX] = acc3[r] * inv;
  }
}

// ---------------------------------------------------------------------------
// Depthwise 3x3 on v_img (= v slice of qkv) + affine; accumulate into att_buf.
// ---------------------------------------------------------------------------
__global__ __launch_bounds__(256) void pe_kernel(
    const float* __restrict__ qkv, const float* __restrict__ w,
    const float* __restrict__ s, const float* __restrict__ bi,
    float* __restrict__ att) {
  const int idx = blockIdx.x * 256 + threadIdx.x;
  const int pix = idx & 1023;
  const int ch  = (idx >> 10) & 255;
  const int b   = idx >> 18;
  const int hh = pix >> 5, ww = pix & 31;
  const int row = ((ch >> 6) * 128) + 64 + (ch & 63);
  const float* vimg = qkv + ((size_t)b * 512 + row) * NPIX;
  float acc = 0.f;
#pragma unroll
  for (int dy = -1; dy <= 1; ++dy)
#pragma unroll
    for (int dx = -1; dx <= 1; ++dx) {
      int y = hh + dy, x = ww + dx;
      if (y >= 0 && y < 32 && x >= 0 && x < 32)
        acc = fmaf(w[ch * 9 + (dy + 1) * 3 + (dx + 1)], vimg[(y << 5) + x], acc);
    }
  att[idx] += fmaf(acc, s[ch], bi[ch]);
}

// ---------------------------------------------------------------------------
// Depthwise 3x3 on y_pin (1024 ch) fused with GLU: g = gelu(dw(c)) * dw(c+512)
// ---------------------------------------------------------------------------
__global__ __launch_bounds__(256) void dwglu_kernel(
    const float* __restrict__ y, const float* __restrict__ w,
    float* __restrict__ g) {
  const int idx = blockIdx.x * 256 + threadIdx.x;
  const int pix = idx & 1023;
  const int c   = (idx >> 10) & 511;
  const int b   = idx >> 19;
  const int hh = pix >> 5, ww = pix & 31;
  const float* y1 = y + ((size_t)b * 1024 + c) * NPIX;
  const float* y2 = y1 + (size_t)512 * NPIX;
  const float* w1 = w + c * 9;
  const float* w2 = w + (512 + c) * 9;
  float s1 = 0.f, s2 = 0.f;
#pragma unroll
  for (int dy = -1; dy <= 1; ++dy)
#pragma unroll
    for (int dx = -1; dx <= 1; ++dx) {
      int yy = hh + dy, xx = ww + dx;
      if (yy >= 0 && yy < 32 && xx >= 0 && xx < 32) {
        const int off = (yy << 5) + xx;
        const int k = (dy + 1) * 3 + (dx + 1);
        s1 = fmaf(w1[k], y1[off], s1);
        s2 = fmaf(w2[k], y2[off], s2);
      }
    }
  const float ge = 0.5f * s1 * (1.f + erff(s1 * 0.70710678118654752f));
  g[idx] = ge * s2;
}

// ---------------------------------------------------------------------------
// Build per-channel 8x8 circular-conv kernel from the rfft2 filter.
// ---------------------------------------------------------------------------
__global__ __launch_bounds__(256) void kc_build(
    const float* __restrict__ filt, float* __restrict__ kc) {
  const int gid = blockIdx.x * 256 + threadIdx.x;
  const int c  = gid >> 6;
  const int da = (gid >> 3) & 7;
  const int db = gid & 7;
  const float* F = filt + c * 40;
  float acc = 0.f;
  for (int u = 0; u < 8; ++u)
    for (int v = 0; v <= 4; ++v) {
      const float wv = (v == 0 || v == 4) ? 1.f : 2.f;
      const int ph = (u * da + v * db) & 7;
      acc += wv * F[u * 5 + v] * cosf(0.78539816339744831f * (float)ph);
    }
  kc[gid] = acc * (1.f / 64.f);
}

// ---------------------------------------------------------------------------
// Apply per-channel 8x8 circular conv per spatial tile + final residual add.
// ---------------------------------------------------------------------------
__global__ __launch_bounds__(256) void fft_final_kernel(
    const float* __restrict__ yin, const float* __restrict__ x2,
    const float* __restrict__ kc, float* __restrict__ out) {
  const int bid = blockIdx.x;
  const int gq = bid & 3;
  const int c  = (bid >> 2) & 255;
  const int b  = bid >> 10;
  __shared__ float kc_s[64];
  __shared__ float tile_s[4][64];
  const int t = threadIdx.x;
  if (t < 64) kc_s[t] = kc[(c << 6) + t];
  const int tl   = t >> 6;
  const int tile = (gq << 2) + tl;
  const int hb = tile >> 2, wb = tile & 3;
  const int a = (t >> 3) & 7, bb2 = t & 7;
  const size_t pbase = ((size_t)b * 256 + c) * NPIX;
  const size_t off = pbase + (size_t)((hb << 3) + a) * 32 + (wb << 3) + bb2;
  tile_s[tl][(a << 3) + bb2] = yin[off];
  __syncthreads();
  float acc = 0.f;
#pragma unroll
  for (int ap = 0; ap < 8; ++ap)
#pragma unroll
    for (int bp = 0; bp < 8; ++bp)
      acc = fmaf(kc_s[(((a - ap) & 7) << 3) + ((bb2 - bp) & 7)],
                 tile_s[tl][(ap << 3) + bp], acc);
  out[off] = x2[off] + acc;
}

// ---------------------------------------------------------------------------
extern "C" void kernel_launch(void* const* d_in, const int* in_sizes, int n_in,
                              void* d_out, int out_size, void* d_ws, size_t ws_size,
                              hipStream_t stream) {
  const float* x      = (const float*)d_in[0];
  const float* qkv_w  = (const float*)d_in[1];
  const float* qkv_s  = (const float*)d_in[2];
  const float* qkv_b  = (const float*)d_in[3];
  const float* pe_w   = (const float*)d_in[4];
  const float* pe_s   = (const float*)d_in[5];
  const float* pe_b   = (const float*)d_in[6];
  const float* proj_w = (const float*)d_in[7];
  const float* proj_s = (const float*)d_in[8];
  const float* proj_b = (const float*)d_in[9];
  const float* pin_w  = (const float*)d_in[10];
  const float* dw_w   = (const float*)d_in[11];
  const float* filt   = (const float*)d_in[12];
  const float* pout_w = (const float*)d_in[13];
  float* out = (float*)d_out;
  float* ws  = (float*)d_ws;

  float* qkv_buf = ws;                   // 16*512*1024
  float* att_buf = ws + 8388608;         // 16*256*1024
  float* x2      = ws + 12582912;        // 16*256*1024
  float* y_pin   = ws + 16777216;        // 16*1024*1024
  float* g_buf   = ws;                   // reuse qkv region
  float* y_out   = ws + 8388608;         // reuse att region
  float* kc      = ws + 33554432;        // 256*64

  dim3 blk(256);
  kc_build<<<dim3(64), blk, 0, stream>>>(filt, kc);
  // qkv = affine(qkv_w @ x)            M=512  K=256
  conv1x1_mfma_kernel<<<dim3(8, 4, 16), blk, 0, stream>>>(
      x, qkv_w, qkv_s, qkv_b, nullptr, qkv_buf, 512, 256);
  attn_mfma_kernel<<<dim3(16, 4, 16), blk, 0, stream>>>(qkv_buf, att_buf);
  pe_kernel<<<dim3(16384), blk, 0, stream>>>(qkv_buf, pe_w, pe_s, pe_b, att_buf);
  // x2 = x + affine(proj_w @ att)      M=256  K=256
  conv1x1_mfma_kernel<<<dim3(8, 2, 16), blk, 0, stream>>>(
      att_buf, proj_w, proj_s, proj_b, x, x2, 256, 256);
  // y_pin = pin_w @ x2                 M=1024 K=256
  conv1x1_mfma_kernel<<<dim3(8, 8, 16), blk, 0, stream>>>(
      x2, pin_w, nullptr, nullptr, nullptr, y_pin, 1024, 256);
  dwglu_kernel<<<dim3(32768), blk, 0, stream>>>(y_pin, dw_w, g_buf);
  // y_out = pout_w @ g                 M=256  K=512
  conv1x1_mfma_kernel<<<dim3(8, 2, 16), blk, 0, stream>>>(
      g_buf, pout_w, nullptr, nullptr, nullptr, y_out, 256, 512);
  fft_final_kernel<<<dim3(16384), blk, 0, stream>>>(y_out, x2, kc, out);
}

// Round 6
// 358.503 us; speedup vs baseline: 2.8440x; 1.0370x over previous
//
#include <hip/hip_runtime.h>
#include <math.h>

#define NPIX 1024   // H*W = 32*32

typedef __bf16 bf16x8 __attribute__((ext_vector_type(8)));
typedef float  f32x4  __attribute__((ext_vector_type(4)));

// ---------------------------------------------------------------------------
// bf16-MFMA conv1x1 GEMM: out[b,o,n] = sc[o]*(sum_c W[o,c]*in[b,c,n])+bi[o]
// (+res). 128x128 tile, K-step 32, 4 waves (2x2), wave tile 64x64 = 4x4
// frags of mfma_f32_16x16x32_bf16. LDS rows padded to 80 B -> 2-way banks.
// A = W[o][k] (no transpose), B = in transposed to [n][k] at staging.
// ---------------------------------------------------------------------------
__global__ __launch_bounds__(256) void conv1x1_mfma_kernel(
    const float* __restrict__ in, const float* __restrict__ W,
    const float* __restrict__ sc, const float* __restrict__ bi,
    const float* __restrict__ res, float* __restrict__ out,
    int O, int C) {
  const int b  = blockIdx.z;
  const int o0 = blockIdx.y << 7;
  const int n0 = blockIdx.x << 7;
  const float* inb  = in  + (size_t)b * C * NPIX;
  float*       outb = out + (size_t)b * O * NPIX;
  const float* resb = res ? res + (size_t)b * O * NPIX : nullptr;

  __shared__ __align__(16) __bf16 a_s[128][40];  // [o][k], 80-B pitch
  __shared__ __align__(16) __bf16 b_s[128][40];  // [n][k], 80-B pitch

  const int t    = threadIdx.x;
  const int lane = t & 63;
  const int wv   = t >> 6;
  const int wo   = (wv >> 1) << 6;   // wave o-offset: 0 / 64
  const int wn   = (wv & 1) << 6;    // wave n-offset: 0 / 64
  const int lr   = lane & 15;
  const int g    = lane >> 4;

  // staging roles
  const int ao = t >> 1, ak = (t & 1) << 4;   // A: row ao, k-half ak
  const int bn = t & 127, bk = (t >> 7) << 4; // B: row bn, k-half bk
  const float* wrow = &W[(size_t)(o0 + ao) * C];

  f32x4 acc[4][4];
#pragma unroll
  for (int m = 0; m < 4; ++m)
#pragma unroll
    for (int n = 0; n < 4; ++n) acc[m][n] = (f32x4){0.f, 0.f, 0.f, 0.f};

  for (int k0 = 0; k0 < C; k0 += 32) {
    __syncthreads();  // previous step's fragment reads done
    // ---- stage A: 16 f32 -> bf16, two 16-B LDS writes ----
    {
      const float* wp = wrow + k0 + ak;
#pragma unroll
      for (int half = 0; half < 2; ++half) {
        float4 lo = *(const float4*)&wp[half * 8];
        float4 hi = *(const float4*)&wp[half * 8 + 4];
        union { __bf16 h[8]; uint4 u; } pk;
        pk.h[0] = (__bf16)lo.x; pk.h[1] = (__bf16)lo.y;
        pk.h[2] = (__bf16)lo.z; pk.h[3] = (__bf16)lo.w;
        pk.h[4] = (__bf16)hi.x; pk.h[5] = (__bf16)hi.y;
        pk.h[6] = (__bf16)hi.z; pk.h[7] = (__bf16)hi.w;
        *(uint4*)((char*)&a_s[ao][ak] + half * 16) = pk.u;
      }
    }
    // ---- stage B: transpose [k][n] -> [n][k], 4x (4 loads -> 8-B write) ----
    {
#pragma unroll
      for (int p = 0; p < 4; ++p) {
        const int kk = k0 + bk + (p << 2);
        union { __bf16 h[4]; uint2 u; } pk;
        pk.h[0] = (__bf16)inb[(size_t)(kk + 0) * NPIX + n0 + bn];
        pk.h[1] = (__bf16)inb[(size_t)(kk + 1) * NPIX + n0 + bn];
        pk.h[2] = (__bf16)inb[(size_t)(kk + 2) * NPIX + n0 + bn];
        pk.h[3] = (__bf16)inb[(size_t)(kk + 3) * NPIX + n0 + bn];
        *(uint2*)((char*)&b_s[bn][bk] + (p << 3)) = pk.u;
      }
    }
    __syncthreads();
    // ---- fragments + 16 MFMAs ----
    bf16x8 af[4], bfr[4];
#pragma unroll
    for (int m = 0; m < 4; ++m)
      af[m] = *(const bf16x8*)((const char*)&a_s[wo + (m << 4) + lr][0] + (g << 4));
#pragma unroll
    for (int n = 0; n < 4; ++n)
      bfr[n] = *(const bf16x8*)((const char*)&b_s[wn + (n << 4) + lr][0] + (g << 4));
#pragma unroll
    for (int m = 0; m < 4; ++m)
#pragma unroll
      for (int n = 0; n < 4; ++n)
        acc[m][n] = __builtin_amdgcn_mfma_f32_16x16x32_bf16(
            af[m], bfr[n], acc[m][n], 0, 0, 0);
  }

  // ---- epilogue: scale/bias/residual in f32, coalesced stores ----
#pragma unroll
  for (int m = 0; m < 4; ++m) {
#pragma unroll
    for (int r = 0; r < 4; ++r) {
      const int o = o0 + wo + (m << 4) + (g << 2) + r;
      const float s  = sc ? sc[o] : 1.f;
      const float bb = bi ? bi[o] : 0.f;
      float* orow = &outb[(size_t)o * NPIX];
      const float* rrow = resb ? &resb[(size_t)o * NPIX] : nullptr;
#pragma unroll
      for (int n = 0; n < 4; ++n) {
        const int nn = n0 + wn + (n << 4) + lr;
        float v = fmaf(acc[m][n][r], s, bb);
        if (rrow) v += rrow[nn];
        orow[nn] = v;
      }
    }
  }
}

// ---------------------------------------------------------------------------
// bf16-MFMA flash attention, v2.
//  * XCD-aware 1-D grid: all 16 query tiles of one (b,h) land on one XCD
//    (L&7 = XCD per round-robin dispatch) -> K/V fetched by a single L2.
//  * KT tile: pitch 128 B, XOR swizzle byte = m*128 + ((4*cp)^((m&7)<<4)).
//    Staging thread = channel-pair cp x 4 spread rows (m = rq+16i): 4-B
//    word writes land 2 lanes/bank (free); b128 frag reads at
//    m*128 + ((g^(m&7))<<4) are element-exact inverse (hand-verified).
//  * V tile unchanged (pitch 128 B, XOR (d&7)<<4), already near optimum.
// ---------------------------------------------------------------------------
__global__ __launch_bounds__(256) void attn_mfma_kernel(
    const float* __restrict__ qkv, float* __restrict__ outbuf) {
  const int L    = blockIdx.x;        // 0..1023
  const int xcd  = L & 7;
  const int rrr  = L >> 3;
  const int tile = rrr & 15;
  const int bh   = xcd + ((rrr >> 4) << 3);
  const int h    = bh & 3;
  const int b    = bh >> 2;
  const int n0   = tile << 6;
  const float scale = 0.1767766952966369f;  // 1/sqrt(32)
  const float* base = qkv + ((size_t)b * 512 + h * 128) * NPIX;

  __shared__ __align__(16) char kt_b[64 * 128];  // KT[m][c] bf16, XOR-swz
  __shared__ __align__(16) char v_b[64 * 128];   // V[d][m] bf16, XOR-swz

  const int t    = threadIdx.x;
  const int w    = t >> 6;
  const int lane = t & 63;
  const int lq   = lane & 15;
  const int g    = lane >> 4;

  // Q B-frag (persistent): q[c=8g+j][n0+16w+lq] * scale
  bf16x8 qf;
  {
    const float* qp = base + (size_t)(g << 3) * NPIX + n0 + (w << 4) + lq;
#pragma unroll
    for (int j = 0; j < 8; ++j)
      qf[j] = (__bf16)(qp[(size_t)j * NPIX] * scale);
  }

  // KT staging roles: channel pair cp, spread rows rq+16i
  const int cp = t >> 4;             // 0..15
  const int rq = t & 15;             // 0..15
  const float* kr0 = base + (size_t)(32 + (cp << 1)) * NPIX;
  const float* kr1 = kr0 + NPIX;
  const int koff = (cp << 2) ^ ((rq & 7) << 4);
  // V staging roles
  const int vd  = t >> 2;            // 0..63 (d row)
  const int vmb = (t & 3) << 4;      // m base (16 per thread)
  const float* vrow = base + (size_t)(64 + vd) * NPIX;
  const int vswz = (vd & 7) << 4;    // byte XOR for V rows

  float m_run = -3.0e38f, l_run = 0.f;
  f32x4 acc0 = {0.f, 0.f, 0.f, 0.f}, acc1 = acc0, acc2 = acc0, acc3 = acc0;

  const int laneA = ((lane & 16) << 1) | lq;   // 32*(g&1) + lq
  const bool hi5  = (lane & 32) != 0;

  for (int mt = 0; mt < 16; ++mt) {
    const int m0 = mt << 6;
    __syncthreads();  // previous tile's reads done before overwrite
    // ---- stage KT: 2 channels x 4 spread rows, 4-B word writes ----
#pragma unroll
    for (int i = 0; i < 4; ++i) {
      const int m = rq + (i << 4);
      union { __bf16 h2[2]; unsigned u; } pk;
      pk.h2[0] = (__bf16)kr0[m0 + m];
      pk.h2[1] = (__bf16)kr1[m0 + m];
      *(unsigned*)(kt_b + (m << 7) + koff) = pk.u;
    }
    // ---- stage V (bf16, swizzled) ----
#pragma unroll
    for (int i4 = 0; i4 < 4; ++i4) {
      float4 v4 = *(const float4*)&vrow[m0 + vmb + (i4 << 2)];
      union { __bf16 h[4]; uint2 u; } pk;
      pk.h[0] = (__bf16)v4.x; pk.h[1] = (__bf16)v4.y;
      pk.h[2] = (__bf16)v4.z; pk.h[3] = (__bf16)v4.w;
      const int mby = (vmb + (i4 << 2)) << 1;  // byte col = 2*m
      *(uint2*)(v_b + (vd << 7) + (mby ^ vswz)) = pk.u;
    }
    __syncthreads();

    // ---- QK^T (swapped): st[tt] = S^T[16tt+4g+r][q=lq], scaled ----
    f32x4 st[4];
#pragma unroll
    for (int tt = 0; tt < 4; ++tt) {
      const int m = (tt << 4) + lq;
      const bf16x8 kfrag = *(const bf16x8*)(
          kt_b + (m << 7) + ((g ^ (lq & 7)) << 4));
      st[tt] = __builtin_amdgcn_mfma_f32_16x16x32_bf16(
          kfrag, qf, (f32x4){0.f, 0.f, 0.f, 0.f}, 0, 0, 0);
    }

    // ---- online softmax (per query = per lane col) ----
    float tmax = -3.0e38f;
#pragma unroll
    for (int tt = 0; tt < 4; ++tt)
#pragma unroll
      for (int r = 0; r < 4; ++r) tmax = fmaxf(tmax, st[tt][r]);
    tmax = fmaxf(tmax, __shfl_xor(tmax, 16));
    tmax = fmaxf(tmax, __shfl_xor(tmax, 32));
    const float mnew  = fmaxf(m_run, tmax);
    const float alpha = __expf(m_run - mnew);
    float ssum = 0.f;
#pragma unroll
    for (int tt = 0; tt < 4; ++tt)
#pragma unroll
      for (int r = 0; r < 4; ++r) {
        st[tt][r] = __expf(st[tt][r] - mnew);
        ssum += st[tt][r];
      }
    ssum += __shfl_xor(ssum, 16);
    ssum += __shfl_xor(ssum, 32);
    l_run = l_run * alpha + ssum;
    m_run = mnew;
    acc0 *= alpha; acc1 *= alpha; acc2 *= alpha; acc3 *= alpha;

    // ---- PV: out^T += mfma(V-frag, P^T-frag) ----
#pragma unroll
    for (int s = 0; s < 2; ++s) {
      bf16x8 pf;
#pragma unroll
      for (int r = 0; r < 4; ++r) {
        const float aL = __shfl(st[2 * s][r],     laneA);
        const float aH = __shfl(st[2 * s + 1][r], laneA);
        const float bL = __shfl(st[2 * s][r],     laneA + 16);
        const float bH = __shfl(st[2 * s + 1][r], laneA + 16);
        pf[r]     = (__bf16)(hi5 ? aH : aL);
        pf[r + 4] = (__bf16)(hi5 ? bH : bL);
      }
      const int cb = ((g << 4) + (s << 6));
#pragma unroll
      for (int dt = 0; dt < 4; ++dt) {
        const int row = (dt << 4) + lq;
        const bf16x8 vfrag = *(const bf16x8*)(
            v_b + (row << 7) + (cb ^ ((lq & 7) << 4)));
        f32x4& a = (dt == 0) ? acc0 : (dt == 1) ? acc1 : (dt == 2) ? acc2 : acc3;
        a = __builtin_amdgcn_mfma_f32_16x16x32_bf16(vfrag, pf, a, 0, 0, 0);
      }
    }
  }

  // ---- epilogue: out[d][n] = acc^T / l ----
  const float inv = 1.f / l_run;
  float* op = outbuf + ((size_t)b * 256 + h * 64) * NPIX + n0 + (w << 4) + lq;
#pragma unroll
  for (int r = 0; r < 4; ++r) {
    op[(size_t)((0 << 4) + (g << 2) + r) * NPIX] = acc0[r] * inv;
    op[(size_t)((1 << 4) + (g << 2) + r) * NPIX] = acc1[r] * inv;
    op[(size_t)((2 << 4) + (g << 2) + r) * NPIX] = acc2[r] * inv;
    op[(size_t)((3 << 4) + (g << 2) + r) * NPIX] = acc3[r] * inv;
  }
}

// ---------------------------------------------------------------------------
// Depthwise 3x3 on v_img (= v slice of qkv) + affine; accumulate into att_buf.
// ---------------------------------------------------------------------------
__global__ __launch_bounds__(256) void pe_kernel(
    const float* __restrict__ qkv, const float* __restrict__ w,
    const float* __restrict__ s, const float* __restrict__ bi,
    float* __restrict__ att) {
  const int idx = blockIdx.x * 256 + threadIdx.x;
  const int pix = idx & 1023;
  const int ch  = (idx >> 10) & 255;
  const int b   = idx >> 18;
  const int hh = pix >> 5, ww = pix & 31;
  const int row = ((ch >> 6) * 128) + 64 + (ch & 63);
  const float* vimg = qkv + ((size_t)b * 512 + row) * NPIX;
  float acc = 0.f;
#pragma unroll
  for (int dy = -1; dy <= 1; ++dy)
#pragma unroll
    for (int dx = -1; dx <= 1; ++dx) {
      int y = hh + dy, x = ww + dx;
      if (y >= 0 && y < 32 && x >= 0 && x < 32)
        acc = fmaf(w[ch * 9 + (dy + 1) * 3 + (dx + 1)], vimg[(y << 5) + x], acc);
    }
  att[idx] += fmaf(acc, s[ch], bi[ch]);
}

// ---------------------------------------------------------------------------
// Depthwise 3x3 on y_pin (1024 ch) fused with GLU: g = gelu(dw(c)) * dw(c+512)
// ---------------------------------------------------------------------------
__global__ __launch_bounds__(256) void dwglu_kernel(
    const float* __restrict__ y, const float* __restrict__ w,
    float* __restrict__ g) {
  const int idx = blockIdx.x * 256 + threadIdx.x;
  const int pix = idx & 1023;
  const int c   = (idx >> 10) & 511;
  const int b   = idx >> 19;
  const int hh = pix >> 5, ww = pix & 31;
  const float* y1 = y + ((size_t)b * 1024 + c) * NPIX;
  const float* y2 = y1 + (size_t)512 * NPIX;
  const float* w1 = w + c * 9;
  const float* w2 = w + (512 + c) * 9;
  float s1 = 0.f, s2 = 0.f;
#pragma unroll
  for (int dy = -1; dy <= 1; ++dy)
#pragma unroll
    for (int dx = -1; dx <= 1; ++dx) {
      int yy = hh + dy, xx = ww + dx;
      if (yy >= 0 && yy < 32 && xx >= 0 && xx < 32) {
        const int off = (yy << 5) + xx;
        const int k = (dy + 1) * 3 + (dx + 1);
        s1 = fmaf(w1[k], y1[off], s1);
        s2 = fmaf(w2[k], y2[off], s2);
      }
    }
  const float ge = 0.5f * s1 * (1.f + erff(s1 * 0.70710678118654752f));
  g[idx] = ge * s2;
}

// ---------------------------------------------------------------------------
// Build per-channel 8x8 circular-conv kernel from the rfft2 filter.
// ---------------------------------------------------------------------------
__global__ __launch_bounds__(256) void kc_build(
    const float* __restrict__ filt, float* __restrict__ kc) {
  const int gid = blockIdx.x * 256 + threadIdx.x;
  const int c  = gid >> 6;
  const int da = (gid >> 3) & 7;
  const int db = gid & 7;
  const float* F = filt + c * 40;
  float acc = 0.f;
  for (int u = 0; u < 8; ++u)
    for (int v = 0; v <= 4; ++v) {
      const float wv = (v == 0 || v == 4) ? 1.f : 2.f;
      const int ph = (u * da + v * db) & 7;
      acc += wv * F[u * 5 + v] * cosf(0.78539816339744831f * (float)ph);
    }
  kc[gid] = acc * (1.f / 64.f);
}

// ---------------------------------------------------------------------------
// Apply per-channel 8x8 circular conv per spatial tile + final residual add.
// ---------------------------------------------------------------------------
__global__ __launch_bounds__(256) void fft_final_kernel(
    const float* __restrict__ yin, const float* __restrict__ x2,
    const float* __restrict__ kc, float* __restrict__ out) {
  const int bid = blockIdx.x;
  const int gq = bid & 3;
  const int c  = (bid >> 2) & 255;
  const int b  = bid >> 10;
  __shared__ float kc_s[64];
  __shared__ float tile_s[4][64];
  const int t = threadIdx.x;
  if (t < 64) kc_s[t] = kc[(c << 6) + t];
  const int tl   = t >> 6;
  const int tile = (gq << 2) + tl;
  const int hb = tile >> 2, wb = tile & 3;
  const int a = (t >> 3) & 7, bb2 = t & 7;
  const size_t pbase = ((size_t)b * 256 + c) * NPIX;
  const size_t off = pbase + (size_t)((hb << 3) + a) * 32 + (wb << 3) + bb2;
  tile_s[tl][(a << 3) + bb2] = yin[off];
  __syncthreads();
  float acc = 0.f;
#pragma unroll
  for (int ap = 0; ap < 8; ++ap)
#pragma unroll
    for (int bp = 0; bp < 8; ++bp)
      acc = fmaf(kc_s[(((a - ap) & 7) << 3) + ((bb2 - bp) & 7)],
                 tile_s[tl][(ap << 3) + bp], acc);
  out[off] = x2[off] + acc;
}

// ---------------------------------------------------------------------------
extern "C" void kernel_launch(void* const* d_in, const int* in_sizes, int n_in,
                              void* d_out, int out_size, void* d_ws, size_t ws_size,
                              hipStream_t stream) {
  const float* x      = (const float*)d_in[0];
  const float* qkv_w  = (const float*)d_in[1];
  const float* qkv_s  = (const float*)d_in[2];
  const float* qkv_b  = (const float*)d_in[3];
  const float* pe_w   = (const float*)d_in[4];
  const float* pe_s   = (const float*)d_in[5];
  const float* pe_b   = (const float*)d_in[6];
  const float* proj_w = (const float*)d_in[7];
  const float* proj_s = (const float*)d_in[8];
  const float* proj_b = (const float*)d_in[9];
  const float* pin_w  = (const float*)d_in[10];
  const float* dw_w   = (const float*)d_in[11];
  const float* filt   = (const float*)d_in[12];
  const float* pout_w = (const float*)d_in[13];
  float* out = (float*)d_out;
  float* ws  = (float*)d_ws;

  float* qkv_buf = ws;                   // 16*512*1024
  float* att_buf = ws + 8388608;         // 16*256*1024
  float* x2      = ws + 12582912;        // 16*256*1024
  float* y_pin   = ws + 16777216;        // 16*1024*1024
  float* g_buf   = ws;                   // reuse qkv region
  float* y_out   = ws + 8388608;         // reuse att region
  float* kc      = ws + 33554432;        // 256*64

  dim3 blk(256);
  kc_build<<<dim3(64), blk, 0, stream>>>(filt, kc);
  // qkv = affine(qkv_w @ x)            M=512  K=256
  conv1x1_mfma_kernel<<<dim3(8, 4, 16), blk, 0, stream>>>(
      x, qkv_w, qkv_s, qkv_b, nullptr, qkv_buf, 512, 256);
  attn_mfma_kernel<<<dim3(1024), blk, 0, stream>>>(qkv_buf, att_buf);
  pe_kernel<<<dim3(16384), blk, 0, stream>>>(qkv_buf, pe_w, pe_s, pe_b, att_buf);
  // x2 = x + affine(proj_w @ att)      M=256  K=256
  conv1x1_mfma_kernel<<<dim3(8, 2, 16), blk, 0, stream>>>(
      att_buf, proj_w, proj_s, proj_b, x, x2, 256, 256);
  // y_pin = pin_w @ x2                 M=1024 K=256
  conv1x1_mfma_kernel<<<dim3(8, 8, 16), blk, 0, stream>>>(
      x2, pin_w, nullptr, nullptr, nullptr, y_pin, 1024, 256);
  dwglu_kernel<<<dim3(32768), blk, 0, stream>>>(y_pin, dw_w, g_buf);
  // y_out = pout_w @ g                 M=256  K=512
  conv1x1_mfma_kernel<<<dim3(8, 2, 16), blk, 0, stream>>>(
      g_buf, pout_w, nullptr, nullptr, nullptr, y_out, 256, 512);
  fft_final_kernel<<<dim3(16384), blk, 0, stream>>>(y_out, x2, kc, out);
}

// Round 7
// 353.974 us; speedup vs baseline: 2.8804x; 1.0128x over previous
//
#include <hip/hip_runtime.h>
#include <math.h>

#define NPIX 1024   // H*W = 32*32

typedef __bf16 bf16x8 __attribute__((ext_vector_type(8)));
typedef float  f32x4  __attribute__((ext_vector_type(4)));

// ---------------------------------------------------------------------------
// bf16-MFMA conv1x1 GEMM: out[b,o,n] = sc[o]*(sum_c W[o,c]*in[b,c,n])+bi[o]
// (+res). 128x128 tile, K-step 32, 4 waves (2x2), wave tile 64x64 = 4x4
// frags of mfma_f32_16x16x32_bf16. LDS rows padded to 80 B -> 2-way banks.
// A = W[o][k] (no transpose), B = in transposed to [n][k] at staging.
// ---------------------------------------------------------------------------
__global__ __launch_bounds__(256) void conv1x1_mfma_kernel(
    const float* __restrict__ in, const float* __restrict__ W,
    const float* __restrict__ sc, const float* __restrict__ bi,
    const float* __restrict__ res, float* __restrict__ out,
    int O, int C) {
  const int b  = blockIdx.z;
  const int o0 = blockIdx.y << 7;
  const int n0 = blockIdx.x << 7;
  const float* inb  = in  + (size_t)b * C * NPIX;
  float*       outb = out + (size_t)b * O * NPIX;
  const float* resb = res ? res + (size_t)b * O * NPIX : nullptr;

  __shared__ __align__(16) __bf16 a_s[128][40];  // [o][k], 80-B pitch
  __shared__ __align__(16) __bf16 b_s[128][40];  // [n][k], 80-B pitch

  const int t    = threadIdx.x;
  const int lane = t & 63;
  const int wv   = t >> 6;
  const int wo   = (wv >> 1) << 6;   // wave o-offset: 0 / 64
  const int wn   = (wv & 1) << 6;    // wave n-offset: 0 / 64
  const int lr   = lane & 15;
  const int g    = lane >> 4;

  // staging roles
  const int ao = t >> 1, ak = (t & 1) << 4;   // A: row ao, k-half ak
  const int bn = t & 127, bk = (t >> 7) << 4; // B: row bn, k-half bk
  const float* wrow = &W[(size_t)(o0 + ao) * C];

  f32x4 acc[4][4];
#pragma unroll
  for (int m = 0; m < 4; ++m)
#pragma unroll
    for (int n = 0; n < 4; ++n) acc[m][n] = (f32x4){0.f, 0.f, 0.f, 0.f};

  for (int k0 = 0; k0 < C; k0 += 32) {
    __syncthreads();  // previous step's fragment reads done
    // ---- stage A: 16 f32 -> bf16, two 16-B LDS writes ----
    {
      const float* wp = wrow + k0 + ak;
#pragma unroll
      for (int half = 0; half < 2; ++half) {
        float4 lo = *(const float4*)&wp[half * 8];
        float4 hi = *(const float4*)&wp[half * 8 + 4];
        union { __bf16 h[8]; uint4 u; } pk;
        pk.h[0] = (__bf16)lo.x; pk.h[1] = (__bf16)lo.y;
        pk.h[2] = (__bf16)lo.z; pk.h[3] = (__bf16)lo.w;
        pk.h[4] = (__bf16)hi.x; pk.h[5] = (__bf16)hi.y;
        pk.h[6] = (__bf16)hi.z; pk.h[7] = (__bf16)hi.w;
        *(uint4*)((char*)&a_s[ao][ak] + half * 16) = pk.u;
      }
    }
    // ---- stage B: transpose [k][n] -> [n][k], 4x (4 loads -> 8-B write) ----
    {
#pragma unroll
      for (int p = 0; p < 4; ++p) {
        const int kk = k0 + bk + (p << 2);
        union { __bf16 h[4]; uint2 u; } pk;
        pk.h[0] = (__bf16)inb[(size_t)(kk + 0) * NPIX + n0 + bn];
        pk.h[1] = (__bf16)inb[(size_t)(kk + 1) * NPIX + n0 + bn];
        pk.h[2] = (__bf16)inb[(size_t)(kk + 2) * NPIX + n0 + bn];
        pk.h[3] = (__bf16)inb[(size_t)(kk + 3) * NPIX + n0 + bn];
        *(uint2*)((char*)&b_s[bn][bk] + (p << 3)) = pk.u;
      }
    }
    __syncthreads();
    // ---- fragments + 16 MFMAs ----
    bf16x8 af[4], bfr[4];
#pragma unroll
    for (int m = 0; m < 4; ++m)
      af[m] = *(const bf16x8*)((const char*)&a_s[wo + (m << 4) + lr][0] + (g << 4));
#pragma unroll
    for (int n = 0; n < 4; ++n)
      bfr[n] = *(const bf16x8*)((const char*)&b_s[wn + (n << 4) + lr][0] + (g << 4));
#pragma unroll
    for (int m = 0; m < 4; ++m)
#pragma unroll
      for (int n = 0; n < 4; ++n)
        acc[m][n] = __builtin_amdgcn_mfma_f32_16x16x32_bf16(
            af[m], bfr[n], acc[m][n], 0, 0, 0);
  }

  // ---- epilogue: scale/bias/residual in f32, coalesced stores ----
#pragma unroll
  for (int m = 0; m < 4; ++m) {
#pragma unroll
    for (int r = 0; r < 4; ++r) {
      const int o = o0 + wo + (m << 4) + (g << 2) + r;
      const float s  = sc ? sc[o] : 1.f;
      const float bb = bi ? bi[o] : 0.f;
      float* orow = &outb[(size_t)o * NPIX];
      const float* rrow = resb ? &resb[(size_t)o * NPIX] : nullptr;
#pragma unroll
      for (int n = 0; n < 4; ++n) {
        const int nn = n0 + wn + (n << 4) + lr;
        float v = fmaf(acc[m][n][r], s, bb);
        if (rrow) v += rrow[nn];
        orow[nn] = v;
      }
    }
  }
}

// ---------------------------------------------------------------------------
// bf16-MFMA flash attention, v3.
//  * XCD-aware 1-D grid (one (b,h)'s 16 query tiles on one XCD L2).
//  * KT tile: pitch 128 B, XOR swizzle (2-way write, b128 reads at floor).
//  * V tile v3: same element layout (byte 2m ^ ((d&7)<<4) in row d), but
//    staging role = (vn = t&15 -> byte col vn*8, rows vd = (t>>4)+16i):
//    each wave writes 4 complete 128-B rows per instruction -> every bank
//    exactly once per row = structural floor, zero write conflicts.
// ---------------------------------------------------------------------------
__global__ __launch_bounds__(256) void attn_mfma_kernel(
    const float* __restrict__ qkv, float* __restrict__ outbuf) {
  const int L    = blockIdx.x;        // 0..1023
  const int xcd  = L & 7;
  const int rrr  = L >> 3;
  const int tile = rrr & 15;
  const int bh   = xcd + ((rrr >> 4) << 3);
  const int h    = bh & 3;
  const int b    = bh >> 2;
  const int n0   = tile << 6;
  const float scale = 0.1767766952966369f;  // 1/sqrt(32)
  const float* base = qkv + ((size_t)b * 512 + h * 128) * NPIX;

  __shared__ __align__(16) char kt_b[64 * 128];  // KT[m][c] bf16, XOR-swz
  __shared__ __align__(16) char v_b[64 * 128];   // V[d][m] bf16, XOR-swz

  const int t    = threadIdx.x;
  const int w    = t >> 6;
  const int lane = t & 63;
  const int lq   = lane & 15;
  const int g    = lane >> 4;

  // Q B-frag (persistent): q[c=8g+j][n0+16w+lq] * scale
  bf16x8 qf;
  {
    const float* qp = base + (size_t)(g << 3) * NPIX + n0 + (w << 4) + lq;
#pragma unroll
    for (int j = 0; j < 8; ++j)
      qf[j] = (__bf16)(qp[(size_t)j * NPIX] * scale);
  }

  // KT staging roles: channel pair cp, spread rows rq+16i
  const int cp = t >> 4;             // 0..15
  const int rq = t & 15;             // 0..15
  const float* kr0 = base + (size_t)(32 + (cp << 1)) * NPIX;
  const float* kr1 = kr0 + NPIX;
  const int koff = (cp << 2) ^ ((rq & 7) << 4);
  // V staging roles (v3): column slot vn, base row vr; rows vr+16i
  const int vn = t & 15;             // byte col = vn*8 (m = 4vn..4vn+3)
  const int vr = t >> 4;             // 0..15
  const float* vrp = base + (size_t)(64 + vr) * NPIX;  // rows +16i -> +16*NPIX

  float m_run = -3.0e38f, l_run = 0.f;
  f32x4 acc0 = {0.f, 0.f, 0.f, 0.f}, acc1 = acc0, acc2 = acc0, acc3 = acc0;

  const int laneA = ((lane & 16) << 1) | lq;   // 32*(g&1) + lq
  const bool hi5  = (lane & 32) != 0;

  for (int mt = 0; mt < 16; ++mt) {
    const int m0 = mt << 6;
    __syncthreads();  // previous tile's reads done before overwrite
    // ---- stage KT: 2 channels x 4 spread rows, 4-B word writes ----
#pragma unroll
    for (int i = 0; i < 4; ++i) {
      const int m = rq + (i << 4);
      union { __bf16 h2[2]; unsigned u; } pk;
      pk.h2[0] = (__bf16)kr0[m0 + m];
      pk.h2[1] = (__bf16)kr1[m0 + m];
      *(unsigned*)(kt_b + (m << 7) + koff) = pk.u;
    }
    // ---- stage V: 4 full rows per wave-instruction (conflict-free) ----
#pragma unroll
    for (int i = 0; i < 4; ++i) {
      const int vd = vr + (i << 4);
      float4 v4 = *(const float4*)&vrp[(size_t)(i << 4) * NPIX + m0 + (vn << 2)];
      union { __bf16 h[4]; uint2 u; } pk;
      pk.h[0] = (__bf16)v4.x; pk.h[1] = (__bf16)v4.y;
      pk.h[2] = (__bf16)v4.z; pk.h[3] = (__bf16)v4.w;
      *(uint2*)(v_b + (vd << 7) + ((vn << 3) ^ ((vd & 7) << 4))) = pk.u;
    }
    __syncthreads();

    // ---- QK^T (swapped): st[tt] = S^T[16tt+4g+r][q=lq], scaled ----
    f32x4 st[4];
#pragma unroll
    for (int tt = 0; tt < 4; ++tt) {
      const int m = (tt << 4) + lq;
      const bf16x8 kfrag = *(const bf16x8*)(
          kt_b + (m << 7) + ((g ^ (lq & 7)) << 4));
      st[tt] = __builtin_amdgcn_mfma_f32_16x16x32_bf16(
          kfrag, qf, (f32x4){0.f, 0.f, 0.f, 0.f}, 0, 0, 0);
    }

    // ---- online softmax (per query = per lane col) ----
    float tmax = -3.0e38f;
#pragma unroll
    for (int tt = 0; tt < 4; ++tt)
#pragma unroll
      for (int r = 0; r < 4; ++r) tmax = fmaxf(tmax, st[tt][r]);
    tmax = fmaxf(tmax, __shfl_xor(tmax, 16));
    tmax = fmaxf(tmax, __shfl_xor(tmax, 32));
    const float mnew  = fmaxf(m_run, tmax);
    const float alpha = __expf(m_run - mnew);
    float ssum = 0.f;
#pragma unroll
    for (int tt = 0; tt < 4; ++tt)
#pragma unroll
      for (int r = 0; r < 4; ++r) {
        st[tt][r] = __expf(st[tt][r] - mnew);
        ssum += st[tt][r];
      }
    ssum += __shfl_xor(ssum, 16);
    ssum += __shfl_xor(ssum, 32);
    l_run = l_run * alpha + ssum;
    m_run = mnew;
    acc0 *= alpha; acc1 *= alpha; acc2 *= alpha; acc3 *= alpha;

    // ---- PV: out^T += mfma(V-frag, P^T-frag) ----
#pragma unroll
    for (int s = 0; s < 2; ++s) {
      bf16x8 pf;
#pragma unroll
      for (int r = 0; r < 4; ++r) {
        const float aL = __shfl(st[2 * s][r],     laneA);
        const float aH = __shfl(st[2 * s + 1][r], laneA);
        const float bL = __shfl(st[2 * s][r],     laneA + 16);
        const float bH = __shfl(st[2 * s + 1][r], laneA + 16);
        pf[r]     = (__bf16)(hi5 ? aH : aL);
        pf[r + 4] = (__bf16)(hi5 ? bH : bL);
      }
      const int cb = ((g << 4) + (s << 6));
#pragma unroll
      for (int dt = 0; dt < 4; ++dt) {
        const int row = (dt << 4) + lq;
        const bf16x8 vfrag = *(const bf16x8*)(
            v_b + (row << 7) + (cb ^ ((lq & 7) << 4)));
        f32x4& a = (dt == 0) ? acc0 : (dt == 1) ? acc1 : (dt == 2) ? acc2 : acc3;
        a = __builtin_amdgcn_mfma_f32_16x16x32_bf16(vfrag, pf, a, 0, 0, 0);
      }
    }
  }

  // ---- epilogue: out[d][n] = acc^T / l ----
  const float inv = 1.f / l_run;
  float* op = outbuf + ((size_t)b * 256 + h * 64) * NPIX + n0 + (w << 4) + lq;
#pragma unroll
  for (int r = 0; r < 4; ++r) {
    op[(size_t)((0 << 4) + (g << 2) + r) * NPIX] = acc0[r] * inv;
    op[(size_t)((1 << 4) + (g << 2) + r) * NPIX] = acc1[r] * inv;
    op[(size_t)((2 << 4) + (g << 2) + r) * NPIX] = acc2[r] * inv;
    op[(size_t)((3 << 4) + (g << 2) + r) * NPIX] = acc3[r] * inv;
  }
}

// ---------------------------------------------------------------------------
// Depthwise 3x3 on v_img (= v slice of qkv) + affine; accumulate into att_buf.
// ---------------------------------------------------------------------------
__global__ __launch_bounds__(256) void pe_kernel(
    const float* __restrict__ qkv, const float* __restrict__ w,
    const float* __restrict__ s, const float* __restrict__ bi,
    float* __restrict__ att) {
  const int idx = blockIdx.x * 256 + threadIdx.x;
  const int pix = idx & 1023;
  const int ch  = (idx >> 10) & 255;
  const int b   = idx >> 18;
  const int hh = pix >> 5, ww = pix & 31;
  const int row = ((ch >> 6) * 128) + 64 + (ch & 63);
  const float* vimg = qkv + ((size_t)b * 512 + row) * NPIX;
  float acc = 0.f;
#pragma unroll
  for (int dy = -1; dy <= 1; ++dy)
#pragma unroll
    for (int dx = -1; dx <= 1; ++dx) {
      int y = hh + dy, x = ww + dx;
      if (y >= 0 && y < 32 && x >= 0 && x < 32)
        acc = fmaf(w[ch * 9 + (dy + 1) * 3 + (dx + 1)], vimg[(y << 5) + x], acc);
    }
  att[idx] += fmaf(acc, s[ch], bi[ch]);
}

// ---------------------------------------------------------------------------
// Depthwise 3x3 on y_pin (1024 ch) fused with GLU: g = gelu(dw(c)) * dw(c+512)
// ---------------------------------------------------------------------------
__global__ __launch_bounds__(256) void dwglu_kernel(
    const float* __restrict__ y, const float* __restrict__ w,
    float* __restrict__ g) {
  const int idx = blockIdx.x * 256 + threadIdx.x;
  const int pix = idx & 1023;
  const int c   = (idx >> 10) & 511;
  const int b   = idx >> 19;
  const int hh = pix >> 5, ww = pix & 31;
  const float* y1 = y + ((size_t)b * 1024 + c) * NPIX;
  const float* y2 = y1 + (size_t)512 * NPIX;
  const float* w1 = w + c * 9;
  const float* w2 = w + (512 + c) * 9;
  float s1 = 0.f, s2 = 0.f;
#pragma unroll
  for (int dy = -1; dy <= 1; ++dy)
#pragma unroll
    for (int dx = -1; dx <= 1; ++dx) {
      int yy = hh + dy, xx = ww + dx;
      if (yy >= 0 && yy < 32 && xx >= 0 && xx < 32) {
        const int off = (yy << 5) + xx;
        const int k = (dy + 1) * 3 + (dx + 1);
        s1 = fmaf(w1[k], y1[off], s1);
        s2 = fmaf(w2[k], y2[off], s2);
      }
    }
  const float ge = 0.5f * s1 * (1.f + erff(s1 * 0.70710678118654752f));
  g[idx] = ge * s2;
}

// ---------------------------------------------------------------------------
// Build per-channel 8x8 circular-conv kernel from the rfft2 filter.
// ---------------------------------------------------------------------------
__global__ __launch_bounds__(256) void kc_build(
    const float* __restrict__ filt, float* __restrict__ kc) {
  const int gid = blockIdx.x * 256 + threadIdx.x;
  const int c  = gid >> 6;
  const int da = (gid >> 3) & 7;
  const int db = gid & 7;
  const float* F = filt + c * 40;
  float acc = 0.f;
  for (int u = 0; u < 8; ++u)
    for (int v = 0; v <= 4; ++v) {
      const float wv = (v == 0 || v == 4) ? 1.f : 2.f;
      const int ph = (u * da + v * db) & 7;
      acc += wv * F[u * 5 + v] * cosf(0.78539816339744831f * (float)ph);
    }
  kc[gid] = acc * (1.f / 64.f);
}

// ---------------------------------------------------------------------------
// Apply per-channel 8x8 circular conv per spatial tile + final residual add.
// ---------------------------------------------------------------------------
__global__ __launch_bounds__(256) void fft_final_kernel(
    const float* __restrict__ yin, const float* __restrict__ x2,
    const float* __restrict__ kc, float* __restrict__ out) {
  const int bid = blockIdx.x;
  const int gq = bid & 3;
  const int c  = (bid >> 2) & 255;
  const int b  = bid >> 10;
  __shared__ float kc_s[64];
  __shared__ float tile_s[4][64];
  const int t = threadIdx.x;
  if (t < 64) kc_s[t] = kc[(c << 6) + t];
  const int tl   = t >> 6;
  const int tile = (gq << 2) + tl;
  const int hb = tile >> 2, wb = tile & 3;
  const int a = (t >> 3) & 7, bb2 = t & 7;
  const size_t pbase = ((size_t)b * 256 + c) * NPIX;
  const size_t off = pbase + (size_t)((hb << 3) + a) * 32 + (wb << 3) + bb2;
  tile_s[tl][(a << 3) + bb2] = yin[off];
  __syncthreads();
  float acc = 0.f;
#pragma unroll
  for (int ap = 0; ap < 8; ++ap)
#pragma unroll
    for (int bp = 0; bp < 8; ++bp)
      acc = fmaf(kc_s[(((a - ap) & 7) << 3) + ((bb2 - bp) & 7)],
                 tile_s[tl][(ap << 3) + bp], acc);
  out[off] = x2[off] + acc;
}

// ---------------------------------------------------------------------------
extern "C" void kernel_launch(void* const* d_in, const int* in_sizes, int n_in,
                              void* d_out, int out_size, void* d_ws, size_t ws_size,
                              hipStream_t stream) {
  const float* x      = (const float*)d_in[0];
  const float* qkv_w  = (const float*)d_in[1];
  const float* qkv_s  = (const float*)d_in[2];
  const float* qkv_b  = (const float*)d_in[3];
  const float* pe_w   = (const float*)d_in[4];
  const float* pe_s   = (const float*)d_in[5];
  const float* pe_b   = (const float*)d_in[6];
  const float* proj_w = (const float*)d_in[7];
  const float* proj_s = (const float*)d_in[8];
  const float* proj_b = (const float*)d_in[9];
  const float* pin_w  = (const float*)d_in[10];
  const float* dw_w   = (const float*)d_in[11];
  const float* filt   = (const float*)d_in[12];
  const float* pout_w = (const float*)d_in[13];
  float* out = (float*)d_out;
  float* ws  = (float*)d_ws;

  float* qkv_buf = ws;                   // 16*512*1024
  float* att_buf = ws + 8388608;         // 16*256*1024
  float* x2      = ws + 12582912;        // 16*256*1024
  float* y_pin   = ws + 16777216;        // 16*1024*1024
  float* g_buf   = ws;                   // reuse qkv region
  float* y_out   = ws + 8388608;         // reuse att region
  float* kc      = ws + 33554432;        // 256*64

  dim3 blk(256);
  kc_build<<<dim3(64), blk, 0, stream>>>(filt, kc);
  // qkv = affine(qkv_w @ x)            M=512  K=256
  conv1x1_mfma_kernel<<<dim3(8, 4, 16), blk, 0, stream>>>(
      x, qkv_w, qkv_s, qkv_b, nullptr, qkv_buf, 512, 256);
  attn_mfma_kernel<<<dim3(1024), blk, 0, stream>>>(qkv_buf, att_buf);
  pe_kernel<<<dim3(16384), blk, 0, stream>>>(qkv_buf, pe_w, pe_s, pe_b, att_buf);
  // x2 = x + affine(proj_w @ att)      M=256  K=256
  conv1x1_mfma_kernel<<<dim3(8, 2, 16), blk, 0, stream>>>(
      att_buf, proj_w, proj_s, proj_b, x, x2, 256, 256);
  // y_pin = pin_w @ x2                 M=1024 K=256
  conv1x1_mfma_kernel<<<dim3(8, 8, 16), blk, 0, stream>>>(
      x2, pin_w, nullptr, nullptr, nullptr, y_pin, 1024, 256);
  dwglu_kernel<<<dim3(32768), blk, 0, stream>>>(y_pin, dw_w, g_buf);
  // y_out = pout_w @ g                 M=256  K=512
  conv1x1_mfma_kernel<<<dim3(8, 2, 16), blk, 0, stream>>>(
      g_buf, pout_w, nullptr, nullptr, nullptr, y_out, 256, 512);
  fft_final_kernel<<<dim3(16384), blk, 0, stream>>>(y_out, x2, kc, out);
}

// Round 9
// 317.921 us; speedup vs baseline: 3.2071x; 1.1134x over previous
//
#include <hip/hip_runtime.h>
#include <math.h>

#define NPIX 1024   // H*W = 32*32

typedef __bf16 bf16x8 __attribute__((ext_vector_type(8)));
typedef float  f32x4  __attribute__((ext_vector_type(4)));

// ---------------------------------------------------------------------------
// bf16-MFMA conv1x1 GEMM: out[b,o,n] = sc[o]*(sum_c W[o,c]*in[b,c,n])+bi[o]
// (+res). 128x128 tile, K-step 32, 4 waves (2x2), wave tile 64x64 = 4x4
// frags of mfma_f32_16x16x32_bf16. LDS rows padded to 80 B -> 2-way banks.
// A = W[o][k] (no transpose), B = in transposed to [n][k] at staging.
// ---------------------------------------------------------------------------
__global__ __launch_bounds__(256) void conv1x1_mfma_kernel(
    const float* __restrict__ in, const float* __restrict__ W,
    const float* __restrict__ sc, const float* __restrict__ bi,
    const float* __restrict__ res, float* __restrict__ out,
    int O, int C) {
  const int b  = blockIdx.z;
  const int o0 = blockIdx.y << 7;
  const int n0 = blockIdx.x << 7;
  const float* inb  = in  + (size_t)b * C * NPIX;
  float*       outb = out + (size_t)b * O * NPIX;
  const float* resb = res ? res + (size_t)b * O * NPIX : nullptr;

  __shared__ __align__(16) __bf16 a_s[128][40];  // [o][k], 80-B pitch
  __shared__ __align__(16) __bf16 b_s[128][40];  // [n][k], 80-B pitch

  const int t    = threadIdx.x;
  const int lane = t & 63;
  const int wv   = t >> 6;
  const int wo   = (wv >> 1) << 6;   // wave o-offset: 0 / 64
  const int wn   = (wv & 1) << 6;    // wave n-offset: 0 / 64
  const int lr   = lane & 15;
  const int g    = lane >> 4;

  // staging roles
  const int ao = t >> 1, ak = (t & 1) << 4;   // A: row ao, k-half ak
  const int bn = t & 127, bk = (t >> 7) << 4; // B: row bn, k-half bk
  const float* wrow = &W[(size_t)(o0 + ao) * C];

  f32x4 acc[4][4];
#pragma unroll
  for (int m = 0; m < 4; ++m)
#pragma unroll
    for (int n = 0; n < 4; ++n) acc[m][n] = (f32x4){0.f, 0.f, 0.f, 0.f};

  for (int k0 = 0; k0 < C; k0 += 32) {
    __syncthreads();  // previous step's fragment reads done
    // ---- stage A: 16 f32 -> bf16, two 16-B LDS writes ----
    {
      const float* wp = wrow + k0 + ak;
#pragma unroll
      for (int half = 0; half < 2; ++half) {
        float4 lo = *(const float4*)&wp[half * 8];
        float4 hi = *(const float4*)&wp[half * 8 + 4];
        union { __bf16 h[8]; uint4 u; } pk;
        pk.h[0] = (__bf16)lo.x; pk.h[1] = (__bf16)lo.y;
        pk.h[2] = (__bf16)lo.z; pk.h[3] = (__bf16)lo.w;
        pk.h[4] = (__bf16)hi.x; pk.h[5] = (__bf16)hi.y;
        pk.h[6] = (__bf16)hi.z; pk.h[7] = (__bf16)hi.w;
        *(uint4*)((char*)&a_s[ao][ak] + half * 16) = pk.u;
      }
    }
    // ---- stage B: transpose [k][n] -> [n][k], 4x (4 loads -> 8-B write) ----
    {
#pragma unroll
      for (int p = 0; p < 4; ++p) {
        const int kk = k0 + bk + (p << 2);
        union { __bf16 h[4]; uint2 u; } pk;
        pk.h[0] = (__bf16)inb[(size_t)(kk + 0) * NPIX + n0 + bn];
        pk.h[1] = (__bf16)inb[(size_t)(kk + 1) * NPIX + n0 + bn];
        pk.h[2] = (__bf16)inb[(size_t)(kk + 2) * NPIX + n0 + bn];
        pk.h[3] = (__bf16)inb[(size_t)(kk + 3) * NPIX + n0 + bn];
        *(uint2*)((char*)&b_s[bn][bk] + (p << 3)) = pk.u;
      }
    }
    __syncthreads();
    // ---- fragments + 16 MFMAs ----
    bf16x8 af[4], bfr[4];
#pragma unroll
    for (int m = 0; m < 4; ++m)
      af[m] = *(const bf16x8*)((const char*)&a_s[wo + (m << 4) + lr][0] + (g << 4));
#pragma unroll
    for (int n = 0; n < 4; ++n)
      bfr[n] = *(const bf16x8*)((const char*)&b_s[wn + (n << 4) + lr][0] + (g << 4));
#pragma unroll
    for (int m = 0; m < 4; ++m)
#pragma unroll
      for (int n = 0; n < 4; ++n)
        acc[m][n] = __builtin_amdgcn_mfma_f32_16x16x32_bf16(
            af[m], bfr[n], acc[m][n], 0, 0, 0);
  }

  // ---- epilogue: scale/bias/residual in f32, coalesced stores ----
#pragma unroll
  for (int m = 0; m < 4; ++m) {
#pragma unroll
    for (int r = 0; r < 4; ++r) {
      const int o = o0 + wo + (m << 4) + (g << 2) + r;
      const float s  = sc ? sc[o] : 1.f;
      const float bb = bi ? bi[o] : 0.f;
      float* orow = &outb[(size_t)o * NPIX];
      const float* rrow = resb ? &resb[(size_t)o * NPIX] : nullptr;
#pragma unroll
      for (int n = 0; n < 4; ++n) {
        const int nn = n0 + wn + (n << 4) + lr;
        float v = fmaf(acc[m][n][r], s, bb);
        if (rrow) v += rrow[nn];
        orow[nn] = v;
      }
    }
  }
}

// ---------------------------------------------------------------------------
// bf16-MFMA flash attention, v3 (unchanged from Round 7).
// ---------------------------------------------------------------------------
__global__ __launch_bounds__(256) void attn_mfma_kernel(
    const float* __restrict__ qkv, float* __restrict__ outbuf) {
  const int L    = blockIdx.x;        // 0..1023
  const int xcd  = L & 7;
  const int rrr  = L >> 3;
  const int tile = rrr & 15;
  const int bh   = xcd + ((rrr >> 4) << 3);
  const int h    = bh & 3;
  const int b    = bh >> 2;
  const int n0   = tile << 6;
  const float scale = 0.1767766952966369f;  // 1/sqrt(32)
  const float* base = qkv + ((size_t)b * 512 + h * 128) * NPIX;

  __shared__ __align__(16) char kt_b[64 * 128];  // KT[m][c] bf16, XOR-swz
  __shared__ __align__(16) char v_b[64 * 128];   // V[d][m] bf16, XOR-swz

  const int t    = threadIdx.x;
  const int w    = t >> 6;
  const int lane = t & 63;
  const int lq   = lane & 15;
  const int g    = lane >> 4;

  // Q B-frag (persistent): q[c=8g+j][n0+16w+lq] * scale
  bf16x8 qf;
  {
    const float* qp = base + (size_t)(g << 3) * NPIX + n0 + (w << 4) + lq;
#pragma unroll
    for (int j = 0; j < 8; ++j)
      qf[j] = (__bf16)(qp[(size_t)j * NPIX] * scale);
  }

  // KT staging roles: channel pair cp, spread rows rq+16i
  const int cp = t >> 4;             // 0..15
  const int rq = t & 15;             // 0..15
  const float* kr0 = base + (size_t)(32 + (cp << 1)) * NPIX;
  const float* kr1 = kr0 + NPIX;
  const int koff = (cp << 2) ^ ((rq & 7) << 4);
  // V staging roles (v3): column slot vn, base row vr; rows vr+16i
  const int vn = t & 15;             // byte col = vn*8 (m = 4vn..4vn+3)
  const int vr = t >> 4;             // 0..15
  const float* vrp = base + (size_t)(64 + vr) * NPIX;  // rows +16i -> +16*NPIX

  float m_run = -3.0e38f, l_run = 0.f;
  f32x4 acc0 = {0.f, 0.f, 0.f, 0.f}, acc1 = acc0, acc2 = acc0, acc3 = acc0;

  const int laneA = ((lane & 16) << 1) | lq;   // 32*(g&1) + lq
  const bool hi5  = (lane & 32) != 0;

  for (int mt = 0; mt < 16; ++mt) {
    const int m0 = mt << 6;
    __syncthreads();  // previous tile's reads done before overwrite
    // ---- stage KT: 2 channels x 4 spread rows, 4-B word writes ----
#pragma unroll
    for (int i = 0; i < 4; ++i) {
      const int m = rq + (i << 4);
      union { __bf16 h2[2]; unsigned u; } pk;
      pk.h2[0] = (__bf16)kr0[m0 + m];
      pk.h2[1] = (__bf16)kr1[m0 + m];
      *(unsigned*)(kt_b + (m << 7) + koff) = pk.u;
    }
    // ---- stage V: 4 full rows per wave-instruction (conflict-free) ----
#pragma unroll
    for (int i = 0; i < 4; ++i) {
      const int vd = vr + (i << 4);
      float4 v4 = *(const float4*)&vrp[(size_t)(i << 4) * NPIX + m0 + (vn << 2)];
      union { __bf16 h[4]; uint2 u; } pk;
      pk.h[0] = (__bf16)v4.x; pk.h[1] = (__bf16)v4.y;
      pk.h[2] = (__bf16)v4.z; pk.h[3] = (__bf16)v4.w;
      *(uint2*)(v_b + (vd << 7) + ((vn << 3) ^ ((vd & 7) << 4))) = pk.u;
    }
    __syncthreads();

    // ---- QK^T (swapped): st[tt] = S^T[16tt+4g+r][q=lq], scaled ----
    f32x4 st[4];
#pragma unroll
    for (int tt = 0; tt < 4; ++tt) {
      const int m = (tt << 4) + lq;
      const bf16x8 kfrag = *(const bf16x8*)(
          kt_b + (m << 7) + ((g ^ (lq & 7)) << 4));
      st[tt] = __builtin_amdgcn_mfma_f32_16x16x32_bf16(
          kfrag, qf, (f32x4){0.f, 0.f, 0.f, 0.f}, 0, 0, 0);
    }

    // ---- online softmax (per query = per lane col) ----
    float tmax = -3.0e38f;
#pragma unroll
    for (int tt = 0; tt < 4; ++tt)
#pragma unroll
      for (int r = 0; r < 4; ++r) tmax = fmaxf(tmax, st[tt][r]);
    tmax = fmaxf(tmax, __shfl_xor(tmax, 16));
    tmax = fmaxf(tmax, __shfl_xor(tmax, 32));
    const float mnew  = fmaxf(m_run, tmax);
    const float alpha = __expf(m_run - mnew);
    float ssum = 0.f;
#pragma unroll
    for (int tt = 0; tt < 4; ++tt)
#pragma unroll
      for (int r = 0; r < 4; ++r) {
        st[tt][r] = __expf(st[tt][r] - mnew);
        ssum += st[tt][r];
      }
    ssum += __shfl_xor(ssum, 16);
    ssum += __shfl_xor(ssum, 32);
    l_run = l_run * alpha + ssum;
    m_run = mnew;
    acc0 *= alpha; acc1 *= alpha; acc2 *= alpha; acc3 *= alpha;

    // ---- PV: out^T += mfma(V-frag, P^T-frag) ----
#pragma unroll
    for (int s = 0; s < 2; ++s) {
      bf16x8 pf;
#pragma unroll
      for (int r = 0; r < 4; ++r) {
        const float aL = __shfl(st[2 * s][r],     laneA);
        const float aH = __shfl(st[2 * s + 1][r], laneA);
        const float bL = __shfl(st[2 * s][r],     laneA + 16);
        const float bH = __shfl(st[2 * s + 1][r], laneA + 16);
        pf[r]     = (__bf16)(hi5 ? aH : aL);
        pf[r + 4] = (__bf16)(hi5 ? bH : bL);
      }
      const int cb = ((g << 4) + (s << 6));
#pragma unroll
      for (int dt = 0; dt < 4; ++dt) {
        const int row = (dt << 4) + lq;
        const bf16x8 vfrag = *(const bf16x8*)(
            v_b + (row << 7) + (cb ^ ((lq & 7) << 4)));
        f32x4& a = (dt == 0) ? acc0 : (dt == 1) ? acc1 : (dt == 2) ? acc2 : acc3;
        a = __builtin_amdgcn_mfma_f32_16x16x32_bf16(vfrag, pf, a, 0, 0, 0);
      }
    }
  }

  // ---- epilogue: out[d][n] = acc^T / l ----
  const float inv = 1.f / l_run;
  float* op = outbuf + ((size_t)b * 256 + h * 64) * NPIX + n0 + (w << 4) + lq;
#pragma unroll
  for (int r = 0; r < 4; ++r) {
    op[(size_t)((0 << 4) + (g << 2) + r) * NPIX] = acc0[r] * inv;
    op[(size_t)((1 << 4) + (g << 2) + r) * NPIX] = acc1[r] * inv;
    op[(size_t)((2 << 4) + (g << 2) + r) * NPIX] = acc2[r] * inv;
    op[(size_t)((3 << 4) + (g << 2) + r) * NPIX] = acc3[r] * inv;
  }
}

// ---------------------------------------------------------------------------
// Depthwise 3x3 on v_img (= v slice of qkv) + affine; accumulate into att_buf.
// ---------------------------------------------------------------------------
__global__ __launch_bounds__(256) void pe_kernel(
    const float* __restrict__ qkv, const float* __restrict__ w,
    const float* __restrict__ s, const float* __restrict__ bi,
    float* __restrict__ att) {
  const int idx = blockIdx.x * 256 + threadIdx.x;
  const int pix = idx & 1023;
  const int ch  = (idx >> 10) & 255;
  const int b   = idx >> 18;
  const int hh = pix >> 5, ww = pix & 31;
  const int row = ((ch >> 6) * 128) + 64 + (ch & 63);
  const float* vimg = qkv + ((size_t)b * 512 + row) * NPIX;
  float acc = 0.f;
#pragma unroll
  for (int dy = -1; dy <= 1; ++dy)
#pragma unroll
    for (int dx = -1; dx <= 1; ++dx) {
      int y = hh + dy, x = ww + dx;
      if (y >= 0 && y < 32 && x >= 0 && x < 32)
        acc = fmaf(w[ch * 9 + (dy + 1) * 3 + (dx + 1)], vimg[(y << 5) + x], acc);
    }
  att[idx] += fmaf(acc, s[ch], bi[ch]);
}

// ---------------------------------------------------------------------------
// Depthwise 3x3 + GLU, v2: one block per (b,c) plane. Stage the 32x32 y1 and
// y2 planes into zero-padded 34x34 LDS tiles (coalesced float4 loads, each
// y_pin element fetched exactly once), then 4 px/thread from LDS.
// g = gelu(dw(y1)) * dw(y2).
// ---------------------------------------------------------------------------
__global__ __launch_bounds__(256) void dwglu_kernel(
    const float* __restrict__ y, const float* __restrict__ w,
    float* __restrict__ g) {
  const int bid = blockIdx.x;        // b*512 + c
  const int c   = bid & 511;
  const int b   = bid >> 9;

  __shared__ float t1[34 * 34];
  __shared__ float t2[34 * 34];
  const int t = threadIdx.x;

  // zero-init (border = SAME zero padding)
  for (int i = t; i < 34 * 34; i += 256) { t1[i] = 0.f; t2[i] = 0.f; }
  __syncthreads();

  const float* y1 = y + ((size_t)b * 1024 + c) * NPIX;
  const float* y2 = y1 + (size_t)512 * NPIX;
  const int r  = t >> 3;            // 0..31
  const int cq = (t & 7) << 2;      // 0,4,..,28
  {
    float4 a1 = *(const float4*)&y1[(r << 5) + cq];
    float4 a2 = *(const float4*)&y2[(r << 5) + cq];
    const int base = (r + 1) * 34 + cq + 1;
    t1[base + 0] = a1.x; t1[base + 1] = a1.y;
    t1[base + 2] = a1.z; t1[base + 3] = a1.w;
    t2[base + 0] = a2.x; t2[base + 1] = a2.y;
    t2[base + 2] = a2.z; t2[base + 3] = a2.w;
  }
  __syncthreads();

  // weights to registers (block-uniform)
  const float* w1 = w + c * 9;
  const float* w2 = w + (512 + c) * 9;
  float W1[9], W2[9];
#pragma unroll
  for (int k = 0; k < 9; ++k) { W1[k] = w1[k]; W2[k] = w2[k]; }

  float4 res;
#pragma unroll
  for (int j = 0; j < 4; ++j) {
    const int x = cq + j;
    float s1 = 0.f, s2 = 0.f;
#pragma unroll
    for (int dy = 0; dy < 3; ++dy)
#pragma unroll
      for (int dx = 0; dx < 3; ++dx) {
        const int idx = (r + dy) * 34 + x + dx;
        const int k   = dy * 3 + dx;
        s1 = fmaf(W1[k], t1[idx], s1);
        s2 = fmaf(W2[k], t2[idx], s2);
      }
    const float ge = 0.5f * s1 * (1.f + erff(s1 * 0.70710678118654752f));
    ((float*)&res)[j] = ge * s2;
  }
  *(float4*)&g[((size_t)b * 512 + c) * NPIX + (r << 5) + cq] = res;
}

// ---------------------------------------------------------------------------
// Build per-channel 8x8 circular-conv kernel from the rfft2 filter.
// ---------------------------------------------------------------------------
__global__ __launch_bounds__(256) void kc_build(
    const float* __restrict__ filt, float* __restrict__ kc) {
  const int gid = blockIdx.x * 256 + threadIdx.x;
  const int c  = gid >> 6;
  const int da = (gid >> 3) & 7;
  const int db = gid & 7;
  const float* F = filt + c * 40;
  float acc = 0.f;
  for (int u = 0; u < 8; ++u)
    for (int v = 0; v <= 4; ++v) {
      const float wv = (v == 0 || v == 4) ? 1.f : 2.f;
      const int ph = (u * da + v * db) & 7;
      acc += wv * F[u * 5 + v] * cosf(0.78539816339744831f * (float)ph);
    }
  kc[gid] = acc * (1.f / 64.f);
}

// ---------------------------------------------------------------------------
// Apply per-channel 8x8 circular conv per spatial tile + final residual add.
// ---------------------------------------------------------------------------
__global__ __launch_bounds__(256) void fft_final_kernel(
    const float* __restrict__ yin, const float* __restrict__ x2,
    const float* __restrict__ kc, float* __restrict__ out) {
  const int bid = blockIdx.x;
  const int gq = bid & 3;
  const int c  = (bid >> 2) & 255;
  const int b  = bid >> 10;
  __shared__ float kc_s[64];
  __shared__ float tile_s[4][64];
  const int t = threadIdx.x;
  if (t < 64) kc_s[t] = kc[(c << 6) + t];
  const int tl   = t >> 6;
  const int tile = (gq << 2) + tl;
  const int hb = tile >> 2, wb = tile & 3;
  const int a = (t >> 3) & 7, bb2 = t & 7;
  const size_t pbase = ((size_t)b * 256 + c) * NPIX;
  const size_t off = pbase + (size_t)((hb << 3) + a) * 32 + (wb << 3) + bb2;
  tile_s[tl][(a << 3) + bb2] = yin[off];
  __syncthreads();
  float acc = 0.f;
#pragma unroll
  for (int ap = 0; ap < 8; ++ap)
#pragma unroll
    for (int bp = 0; bp < 8; ++bp)
      acc = fmaf(kc_s[(((a - ap) & 7) << 3) + ((bb2 - bp) & 7)],
                 tile_s[tl][(ap << 3) + bp], acc);
  out[off] = x2[off] + acc;
}

// ---------------------------------------------------------------------------
extern "C" void kernel_launch(void* const* d_in, const int* in_sizes, int n_in,
                              void* d_out, int out_size, void* d_ws, size_t ws_size,
                              hipStream_t stream) {
  const float* x      = (const float*)d_in[0];
  const float* qkv_w  = (const float*)d_in[1];
  const float* qkv_s  = (const float*)d_in[2];
  const float* qkv_b  = (const float*)d_in[3];
  const float* pe_w   = (const float*)d_in[4];
  const float* pe_s   = (const float*)d_in[5];
  const float* pe_b   = (const float*)d_in[6];
  const float* proj_w = (const float*)d_in[7];
  const float* proj_s = (const float*)d_in[8];
  const float* proj_b = (const float*)d_in[9];
  const float* pin_w  = (const float*)d_in[10];
  const float* dw_w   = (const float*)d_in[11];
  const float* filt   = (const float*)d_in[12];
  const float* pout_w = (const float*)d_in[13];
  float* out = (float*)d_out;
  float* ws  = (float*)d_ws;

  float* qkv_buf = ws;                   // 16*512*1024
  float* att_buf = ws + 8388608;         // 16*256*1024
  float* x2      = ws + 12582912;        // 16*256*1024
  float* y_pin   = ws + 16777216;        // 16*1024*1024
  float* g_buf   = ws;                   // reuse qkv region
  float* y_out   = ws + 8388608;         // reuse att region
  float* kc      = ws + 33554432;        // 256*64

  dim3 blk(256);
  kc_build<<<dim3(64), blk, 0, stream>>>(filt, kc);
  // qkv = affine(qkv_w @ x)            M=512  K=256
  conv1x1_mfma_kernel<<<dim3(8, 4, 16), blk, 0, stream>>>(
      x, qkv_w, qkv_s, qkv_b, nullptr, qkv_buf, 512, 256);
  attn_mfma_kernel<<<dim3(1024), blk, 0, stream>>>(qkv_buf, att_buf);
  pe_kernel<<<dim3(16384), blk, 0, stream>>>(qkv_buf, pe_w, pe_s, pe_b, att_buf);
  // x2 = x + affine(proj_w @ att)      M=256  K=256
  conv1x1_mfma_kernel<<<dim3(8, 2, 16), blk, 0, stream>>>(
      att_buf, proj_w, proj_s, proj_b, x, x2, 256, 256);
  // y_pin = pin_w @ x2                 M=1024 K=256
  conv1x1_mfma_kernel<<<dim3(8, 8, 16), blk, 0, stream>>>(
      x2, pin_w, nullptr, nullptr, nullptr, y_pin, 1024, 256);
  dwglu_kernel<<<dim3(8192), blk, 0, stream>>>(y_pin, dw_w, g_buf);
  // y_out = pout_w @ g                 M=256  K=512
  conv1x1_mfma_kernel<<<dim3(8, 2, 16), blk, 0, stream>>>(
      g_buf, pout_w, nullptr, nullptr, nullptr, y_out, 256, 512);
  fft_final_kernel<<<dim3(16384), blk, 0, stream>>>(y_out, x2, kc, out);
}

// Round 10
// 306.819 us; speedup vs baseline: 3.3231x; 1.0362x over previous
//
#include <hip/hip_runtime.h>
#include <math.h>

#define NPIX 1024   // H*W = 32*32

typedef __bf16 bf16x8 __attribute__((ext_vector_type(8)));
typedef float  f32x4  __attribute__((ext_vector_type(4)));

// ---------------------------------------------------------------------------
// bf16-MFMA conv1x1 GEMM: out[b,o,n] = sc[o]*(sum_c W[o,c]*in[b,c,n])+bi[o]
// (+res). 128x128 tile, K-step 32, 4 waves (2x2), wave tile 64x64 = 4x4
// frags of mfma_f32_16x16x32_bf16. LDS rows padded to 80 B -> 2-way banks.
// A = W[o][k] (no transpose), B = in transposed to [n][k] at staging.
// ---------------------------------------------------------------------------
__global__ __launch_bounds__(256) void conv1x1_mfma_kernel(
    const float* __restrict__ in, const float* __restrict__ W,
    const float* __restrict__ sc, const float* __restrict__ bi,
    const float* __restrict__ res, float* __restrict__ out,
    int O, int C) {
  const int b  = blockIdx.z;
  const int o0 = blockIdx.y << 7;
  const int n0 = blockIdx.x << 7;
  const float* inb  = in  + (size_t)b * C * NPIX;
  float*       outb = out + (size_t)b * O * NPIX;
  const float* resb = res ? res + (size_t)b * O * NPIX : nullptr;

  __shared__ __align__(16) __bf16 a_s[128][40];  // [o][k], 80-B pitch
  __shared__ __align__(16) __bf16 b_s[128][40];  // [n][k], 80-B pitch

  const int t    = threadIdx.x;
  const int lane = t & 63;
  const int wv   = t >> 6;
  const int wo   = (wv >> 1) << 6;   // wave o-offset: 0 / 64
  const int wn   = (wv & 1) << 6;    // wave n-offset: 0 / 64
  const int lr   = lane & 15;
  const int g    = lane >> 4;

  // staging roles
  const int ao = t >> 1, ak = (t & 1) << 4;   // A: row ao, k-half ak
  const int bn = t & 127, bk = (t >> 7) << 4; // B: row bn, k-half bk
  const float* wrow = &W[(size_t)(o0 + ao) * C];

  f32x4 acc[4][4];
#pragma unroll
  for (int m = 0; m < 4; ++m)
#pragma unroll
    for (int n = 0; n < 4; ++n) acc[m][n] = (f32x4){0.f, 0.f, 0.f, 0.f};

  for (int k0 = 0; k0 < C; k0 += 32) {
    __syncthreads();  // previous step's fragment reads done
    // ---- stage A: 16 f32 -> bf16, two 16-B LDS writes ----
    {
      const float* wp = wrow + k0 + ak;
#pragma unroll
      for (int half = 0; half < 2; ++half) {
        float4 lo = *(const float4*)&wp[half * 8];
        float4 hi = *(const float4*)&wp[half * 8 + 4];
        union { __bf16 h[8]; uint4 u; } pk;
        pk.h[0] = (__bf16)lo.x; pk.h[1] = (__bf16)lo.y;
        pk.h[2] = (__bf16)lo.z; pk.h[3] = (__bf16)lo.w;
        pk.h[4] = (__bf16)hi.x; pk.h[5] = (__bf16)hi.y;
        pk.h[6] = (__bf16)hi.z; pk.h[7] = (__bf16)hi.w;
        *(uint4*)((char*)&a_s[ao][ak] + half * 16) = pk.u;
      }
    }
    // ---- stage B: transpose [k][n] -> [n][k], 4x (4 loads -> 8-B write) ----
    {
#pragma unroll
      for (int p = 0; p < 4; ++p) {
        const int kk = k0 + bk + (p << 2);
        union { __bf16 h[4]; uint2 u; } pk;
        pk.h[0] = (__bf16)inb[(size_t)(kk + 0) * NPIX + n0 + bn];
        pk.h[1] = (__bf16)inb[(size_t)(kk + 1) * NPIX + n0 + bn];
        pk.h[2] = (__bf16)inb[(size_t)(kk + 2) * NPIX + n0 + bn];
        pk.h[3] = (__bf16)inb[(size_t)(kk + 3) * NPIX + n0 + bn];
        *(uint2*)((char*)&b_s[bn][bk] + (p << 3)) = pk.u;
      }
    }
    __syncthreads();
    // ---- fragments + 16 MFMAs ----
    bf16x8 af[4], bfr[4];
#pragma unroll
    for (int m = 0; m < 4; ++m)
      af[m] = *(const bf16x8*)((const char*)&a_s[wo + (m << 4) + lr][0] + (g << 4));
#pragma unroll
    for (int n = 0; n < 4; ++n)
      bfr[n] = *(const bf16x8*)((const char*)&b_s[wn + (n << 4) + lr][0] + (g << 4));
#pragma unroll
    for (int m = 0; m < 4; ++m)
#pragma unroll
      for (int n = 0; n < 4; ++n)
        acc[m][n] = __builtin_amdgcn_mfma_f32_16x16x32_bf16(
            af[m], bfr[n], acc[m][n], 0, 0, 0);
  }

  // ---- epilogue: scale/bias/residual in f32, coalesced stores ----
#pragma unroll
  for (int m = 0; m < 4; ++m) {
#pragma unroll
    for (int r = 0; r < 4; ++r) {
      const int o = o0 + wo + (m << 4) + (g << 2) + r;
      const float s  = sc ? sc[o] : 1.f;
      const float bb = bi ? bi[o] : 0.f;
      float* orow = &outb[(size_t)o * NPIX];
      const float* rrow = resb ? &resb[(size_t)o * NPIX] : nullptr;
#pragma unroll
      for (int n = 0; n < 4; ++n) {
        const int nn = n0 + wn + (n << 4) + lr;
        float v = fmaf(acc[m][n][r], s, bb);
        if (rrow) v += rrow[nn];
        orow[nn] = v;
      }
    }
  }
}

// ---------------------------------------------------------------------------
// bf16-MFMA flash attention, v4.
//  * XCD-aware 1-D grid (one (b,h)'s 16 query tiles on one XCD L2).
//  * KT tile: pitch 128 B, XOR swizzle (2-way write, b128 reads at floor).
//  * V tile: row-complete staging (zero write conflicts).
//  * P^T redistribution v4: instead of 32 ds_bpermute (__shfl) + selects per
//    iter, each lane writes its 4 packed bf16 P-values per tt to a
//    WAVE-PRIVATE LDS P-tile (P[q][m], pitch 128 B, XOR ((q&7)<<4)), and the
//    PV B-frag is one b128 read (element-exact inverse, hand-verified).
//    Wave-private region -> no barrier; compiler orders same-array ds ops.
// ---------------------------------------------------------------------------
__global__ __launch_bounds__(256) void attn_mfma_kernel(
    const float* __restrict__ qkv, float* __restrict__ outbuf) {
  const int L    = blockIdx.x;        // 0..1023
  const int xcd  = L & 7;
  const int rrr  = L >> 3;
  const int tile = rrr & 15;
  const int bh   = xcd + ((rrr >> 4) << 3);
  const int h    = bh & 3;
  const int b    = bh >> 2;
  const int n0   = tile << 6;
  const float scale = 0.1767766952966369f;  // 1/sqrt(32)
  const float* base = qkv + ((size_t)b * 512 + h * 128) * NPIX;

  __shared__ __align__(16) char kt_b[64 * 128];   // KT[m][c] bf16, XOR-swz
  __shared__ __align__(16) char v_b[64 * 128];    // V[d][m] bf16, XOR-swz
  __shared__ __align__(16) char p_b[4 * 16 * 128];// P[q][m] bf16/wave, XOR-swz

  const int t    = threadIdx.x;
  const int w    = t >> 6;
  const int lane = t & 63;
  const int lq   = lane & 15;
  const int g    = lane >> 4;

  // Q B-frag (persistent): q[c=8g+j][n0+16w+lq] * scale
  bf16x8 qf;
  {
    const float* qp = base + (size_t)(g << 3) * NPIX + n0 + (w << 4) + lq;
#pragma unroll
    for (int j = 0; j < 8; ++j)
      qf[j] = (__bf16)(qp[(size_t)j * NPIX] * scale);
  }

  // KT staging roles: channel pair cp, spread rows rq+16i
  const int cp = t >> 4;             // 0..15
  const int rq = t & 15;             // 0..15
  const float* kr0 = base + (size_t)(32 + (cp << 1)) * NPIX;
  const float* kr1 = kr0 + NPIX;
  const int koff = (cp << 2) ^ ((rq & 7) << 4);
  // V staging roles: column slot vn, base row vr; rows vr+16i
  const int vn = t & 15;             // byte col = vn*8 (m = 4vn..4vn+3)
  const int vr = t >> 4;             // 0..15
  const float* vrp = base + (size_t)(64 + vr) * NPIX;  // rows +16i -> +16*NPIX

  // wave-private P region
  char* pw = p_b + (w << 11);
  const int pswz = (lq & 7) << 4;

  float m_run = -3.0e38f, l_run = 0.f;
  f32x4 acc0 = {0.f, 0.f, 0.f, 0.f}, acc1 = acc0, acc2 = acc0, acc3 = acc0;

  for (int mt = 0; mt < 16; ++mt) {
    const int m0 = mt << 6;
    __syncthreads();  // previous tile's reads done before overwrite
    // ---- stage KT: 2 channels x 4 spread rows, 4-B word writes ----
#pragma unroll
    for (int i = 0; i < 4; ++i) {
      const int m = rq + (i << 4);
      union { __bf16 h2[2]; unsigned u; } pk;
      pk.h2[0] = (__bf16)kr0[m0 + m];
      pk.h2[1] = (__bf16)kr1[m0 + m];
      *(unsigned*)(kt_b + (m << 7) + koff) = pk.u;
    }
    // ---- stage V: 4 full rows per wave-instruction (conflict-free) ----
#pragma unroll
    for (int i = 0; i < 4; ++i) {
      const int vd = vr + (i << 4);
      float4 v4 = *(const float4*)&vrp[(size_t)(i << 4) * NPIX + m0 + (vn << 2)];
      union { __bf16 h[4]; uint2 u; } pk;
      pk.h[0] = (__bf16)v4.x; pk.h[1] = (__bf16)v4.y;
      pk.h[2] = (__bf16)v4.z; pk.h[3] = (__bf16)v4.w;
      *(uint2*)(v_b + (vd << 7) + ((vn << 3) ^ ((vd & 7) << 4))) = pk.u;
    }
    __syncthreads();

    // ---- QK^T (swapped): st[tt] = S^T[16tt+4g+r][q=lq], scaled ----
    f32x4 st[4];
#pragma unroll
    for (int tt = 0; tt < 4; ++tt) {
      const int m = (tt << 4) + lq;
      const bf16x8 kfrag = *(const bf16x8*)(
          kt_b + (m << 7) + ((g ^ (lq & 7)) << 4));
      st[tt] = __builtin_amdgcn_mfma_f32_16x16x32_bf16(
          kfrag, qf, (f32x4){0.f, 0.f, 0.f, 0.f}, 0, 0, 0);
    }

    // ---- online softmax (per query = per lane col) ----
    float tmax = -3.0e38f;
#pragma unroll
    for (int tt = 0; tt < 4; ++tt)
#pragma unroll
      for (int r = 0; r < 4; ++r) tmax = fmaxf(tmax, st[tt][r]);
    tmax = fmaxf(tmax, __shfl_xor(tmax, 16));
    tmax = fmaxf(tmax, __shfl_xor(tmax, 32));
    const float mnew  = fmaxf(m_run, tmax);
    const float alpha = __expf(m_run - mnew);
    float ssum = 0.f;
#pragma unroll
    for (int tt = 0; tt < 4; ++tt)
#pragma unroll
      for (int r = 0; r < 4; ++r) {
        st[tt][r] = __expf(st[tt][r] - mnew);
        ssum += st[tt][r];
      }
    ssum += __shfl_xor(ssum, 16);
    ssum += __shfl_xor(ssum, 32);
    l_run = l_run * alpha + ssum;
    m_run = mnew;
    acc0 *= alpha; acc1 *= alpha; acc2 *= alpha; acc3 *= alpha;

    // ---- write P[q=lq][m] (bf16, packed 4/tt) to wave-private LDS ----
#pragma unroll
    for (int tt = 0; tt < 4; ++tt) {
      union { __bf16 h[4]; uint2 u; } pk;
      pk.h[0] = (__bf16)st[tt][0]; pk.h[1] = (__bf16)st[tt][1];
      pk.h[2] = (__bf16)st[tt][2]; pk.h[3] = (__bf16)st[tt][3];
      *(uint2*)(pw + (lq << 7) + (((tt << 5) + (g << 3)) ^ pswz)) = pk.u;
    }

    // ---- PV: out^T += mfma(V-frag, P-frag from LDS) ----
#pragma unroll
    for (int s = 0; s < 2; ++s) {
      const bf16x8 pf = *(const bf16x8*)(
          pw + (lq << 7) + (((s << 6) + (g << 4)) ^ pswz));
      const int cb = ((g << 4) + (s << 6));
#pragma unroll
      for (int dt = 0; dt < 4; ++dt) {
        const int row = (dt << 4) + lq;
        const bf16x8 vfrag = *(const bf16x8*)(
            v_b + (row << 7) + (cb ^ ((lq & 7) << 4)));
        f32x4& a = (dt == 0) ? acc0 : (dt == 1) ? acc1 : (dt == 2) ? acc2 : acc3;
        a = __builtin_amdgcn_mfma_f32_16x16x32_bf16(vfrag, pf, a, 0, 0, 0);
      }
    }
  }

  // ---- epilogue: out[d][n] = acc^T / l ----
  const float inv = 1.f / l_run;
  float* op = outbuf + ((size_t)b * 256 + h * 64) * NPIX + n0 + (w << 4) + lq;
#pragma unroll
  for (int r = 0; r < 4; ++r) {
    op[(size_t)((0 << 4) + (g << 2) + r) * NPIX] = acc0[r] * inv;
    op[(size_t)((1 << 4) + (g << 2) + r) * NPIX] = acc1[r] * inv;
    op[(size_t)((2 << 4) + (g << 2) + r) * NPIX] = acc2[r] * inv;
    op[(size_t)((3 << 4) + (g << 2) + r) * NPIX] = acc3[r] * inv;
  }
}

// ---------------------------------------------------------------------------
// Depthwise 3x3 on v_img (= v slice of qkv) + affine; accumulate into att_buf.
// ---------------------------------------------------------------------------
__global__ __launch_bounds__(256) void pe_kernel(
    const float* __restrict__ qkv, const float* __restrict__ w,
    const float* __restrict__ s, const float* __restrict__ bi,
    float* __restrict__ att) {
  const int idx = blockIdx.x * 256 + threadIdx.x;
  const int pix = idx & 1023;
  const int ch  = (idx >> 10) & 255;
  const int b   = idx >> 18;
  const int hh = pix >> 5, ww = pix & 31;
  const int row = ((ch >> 6) * 128) + 64 + (ch & 63);
  const float* vimg = qkv + ((size_t)b * 512 + row) * NPIX;
  float acc = 0.f;
#pragma unroll
  for (int dy = -1; dy <= 1; ++dy)
#pragma unroll
    for (int dx = -1; dx <= 1; ++dx) {
      int y = hh + dy, x = ww + dx;
      if (y >= 0 && y < 32 && x >= 0 && x < 32)
        acc = fmaf(w[ch * 9 + (dy + 1) * 3 + (dx + 1)], vimg[(y << 5) + x], acc);
    }
  att[idx] += fmaf(acc, s[ch], bi[ch]);
}

// ---------------------------------------------------------------------------
// Depthwise 3x3 + GLU: one block per (b,c) plane, 34x34 zero-padded LDS tiles.
// g = gelu(dw(y1)) * dw(y2).
// ---------------------------------------------------------------------------
__global__ __launch_bounds__(256) void dwglu_kernel(
    const float* __restrict__ y, const float* __restrict__ w,
    float* __restrict__ g) {
  const int bid = blockIdx.x;        // b*512 + c
  const int c   = bid & 511;
  const int b   = bid >> 9;

  __shared__ float t1[34 * 34];
  __shared__ float t2[34 * 34];
  const int t = threadIdx.x;

  // zero-init (border = SAME zero padding)
  for (int i = t; i < 34 * 34; i += 256) { t1[i] = 0.f; t2[i] = 0.f; }
  __syncthreads();

  const float* y1 = y + ((size_t)b * 1024 + c) * NPIX;
  const float* y2 = y1 + (size_t)512 * NPIX;
  const int r  = t >> 3;            // 0..31
  const int cq = (t & 7) << 2;      // 0,4,..,28
  {
    float4 a1 = *(const float4*)&y1[(r << 5) + cq];
    float4 a2 = *(const float4*)&y2[(r << 5) + cq];
    const int base = (r + 1) * 34 + cq + 1;
    t1[base + 0] = a1.x; t1[base + 1] = a1.y;
    t1[base + 2] = a1.z; t1[base + 3] = a1.w;
    t2[base + 0] = a2.x; t2[base + 1] = a2.y;
    t2[base + 2] = a2.z; t2[base + 3] = a2.w;
  }
  __syncthreads();

  // weights to registers (block-uniform)
  const float* w1 = w + c * 9;
  const float* w2 = w + (512 + c) * 9;
  float W1[9], W2[9];
#pragma unroll
  for (int k = 0; k < 9; ++k) { W1[k] = w1[k]; W2[k] = w2[k]; }

  float4 res;
#pragma unroll
  for (int j = 0; j < 4; ++j) {
    const int x = cq + j;
    float s1 = 0.f, s2 = 0.f;
#pragma unroll
    for (int dy = 0; dy < 3; ++dy)
#pragma unroll
      for (int dx = 0; dx < 3; ++dx) {
        const int idx = (r + dy) * 34 + x + dx;
        const int k   = dy * 3 + dx;
        s1 = fmaf(W1[k], t1[idx], s1);
        s2 = fmaf(W2[k], t2[idx], s2);
      }
    const float ge = 0.5f * s1 * (1.f + erff(s1 * 0.70710678118654752f));
    ((float*)&res)[j] = ge * s2;
  }
  *(float4*)&g[((size_t)b * 512 + c) * NPIX + (r << 5) + cq] = res;
}

// ---------------------------------------------------------------------------
// Build per-channel 8x8 circular-conv kernel from the rfft2 filter.
// ---------------------------------------------------------------------------
__global__ __launch_bounds__(256) void kc_build(
    const float* __restrict__ filt, float* __restrict__ kc) {
  const int gid = blockIdx.x * 256 + threadIdx.x;
  const int c  = gid >> 6;
  const int da = (gid >> 3) & 7;
  const int db = gid & 7;
  const float* F = filt + c * 40;
  float acc = 0.f;
  for (int u = 0; u < 8; ++u)
    for (int v = 0; v <= 4; ++v) {
      const float wv = (v == 0 || v == 4) ? 1.f : 2.f;
      const int ph = (u * da + v * db) & 7;
      acc += wv * F[u * 5 + v] * cosf(0.78539816339744831f * (float)ph);
    }
  kc[gid] = acc * (1.f / 64.f);
}

// ---------------------------------------------------------------------------
// Apply per-channel 8x8 circular conv per spatial tile + final residual add.
// ---------------------------------------------------------------------------
__global__ __launch_bounds__(256) void fft_final_kernel(
    const float* __restrict__ yin, const float* __restrict__ x2,
    const float* __restrict__ kc, float* __restrict__ out) {
  const int bid = blockIdx.x;
  const int gq = bid & 3;
  const int c  = (bid >> 2) & 255;
  const int b  = bid >> 10;
  __shared__ float kc_s[64];
  __shared__ float tile_s[4][64];
  const int t = threadIdx.x;
  if (t < 64) kc_s[t] = kc[(c << 6) + t];
  const int tl   = t >> 6;
  const int tile = (gq << 2) + tl;
  const int hb = tile >> 2, wb = tile & 3;
  const int a = (t >> 3) & 7, bb2 = t & 7;
  const size_t pbase = ((size_t)b * 256 + c) * NPIX;
  const size_t off = pbase + (size_t)((hb << 3) + a) * 32 + (wb << 3) + bb2;
  tile_s[tl][(a << 3) + bb2] = yin[off];
  __syncthreads();
  float acc = 0.f;
#pragma unroll
  for (int ap = 0; ap < 8; ++ap)
#pragma unroll
    for (int bp = 0; bp < 8; ++bp)
      acc = fmaf(kc_s[(((a - ap) & 7) << 3) + ((bb2 - bp) & 7)],
                 tile_s[tl][(ap << 3) + bp], acc);
  out[off] = x2[off] + acc;
}

// ---------------------------------------------------------------------------
extern "C" void kernel_launch(void* const* d_in, const int* in_sizes, int n_in,
                              void* d_out, int out_size, void* d_ws, size_t ws_size,
                              hipStream_t stream) {
  const float* x      = (const float*)d_in[0];
  const float* qkv_w  = (const float*)d_in[1];
  const float* qkv_s  = (const float*)d_in[2];
  const float* qkv_b  = (const float*)d_in[3];
  const float* pe_w   = (const float*)d_in[4];
  const float* pe_s   = (const float*)d_in[5];
  const float* pe_b   = (const float*)d_in[6];
  const float* proj_w = (const float*)d_in[7];
  const float* proj_s = (const float*)d_in[8];
  const float* proj_b = (const float*)d_in[9];
  const float* pin_w  = (const float*)d_in[10];
  const float* dw_w   = (const float*)d_in[11];
  const float* filt   = (const float*)d_in[12];
  const float* pout_w = (const float*)d_in[13];
  float* out = (float*)d_out;
  float* ws  = (float*)d_ws;

  float* qkv_buf = ws;                   // 16*512*1024
  float* att_buf = ws + 8388608;         // 16*256*1024
  float* x2      = ws + 12582912;        // 16*256*1024
  float* y_pin   = ws + 16777216;        // 16*1024*1024
  float* g_buf   = ws;                   // reuse qkv region
  float* y_out   = ws + 8388608;         // reuse att region
  float* kc      = ws + 33554432;        // 256*64

  dim3 blk(256);
  kc_build<<<dim3(64), blk, 0, stream>>>(filt, kc);
  // qkv = affine(qkv_w @ x)            M=512  K=256
  conv1x1_mfma_kernel<<<dim3(8, 4, 16), blk, 0, stream>>>(
      x, qkv_w, qkv_s, qkv_b, nullptr, qkv_buf, 512, 256);
  attn_mfma_kernel<<<dim3(1024), blk, 0, stream>>>(qkv_buf, att_buf);
  pe_kernel<<<dim3(16384), blk, 0, stream>>>(qkv_buf, pe_w, pe_s, pe_b, att_buf);
  // x2 = x + affine(proj_w @ att)      M=256  K=256
  conv1x1_mfma_kernel<<<dim3(8, 2, 16), blk, 0, stream>>>(
      att_buf, proj_w, proj_s, proj_b, x, x2, 256, 256);
  // y_pin = pin_w @ x2                 M=1024 K=256
  conv1x1_mfma_kernel<<<dim3(8, 8, 16), blk, 0, stream>>>(
      x2, pin_w, nullptr, nullptr, nullptr, y_pin, 1024, 256);
  dwglu_kernel<<<dim3(8192), blk, 0, stream>>>(y_pin, dw_w, g_buf);
  // y_out = pout_w @ g                 M=256  K=512
  conv1x1_mfma_kernel<<<dim3(8, 2, 16), blk, 0, stream>>>(
      g_buf, pout_w, nullptr, nullptr, nullptr, y_out, 256, 512);
  fft_final_kernel<<<dim3(16384), blk, 0, stream>>>(y_out, x2, kc, out);
}